// Round 1
// baseline (1067.885 us; speedup 1.0000x reference)
//
#include <hip/hip_runtime.h>
#include <math.h>

#define NB 32
#define HW 4096
#define NS 16
#define EDIM 256
#define FFND 1024
#define EPS_LN 1e-5f
#define EPS_ATTN 1e-5f
#define BPB 16           // blocks per batch in bigpass
#define RPB (HW / BPB)   // 256 rows per block

__device__ __forceinline__ float sigmoidf_(float x) { return 1.0f / (1.0f + __expf(-x)); }
__device__ __forceinline__ float gelu_(float x) {
    float x3 = x * x * x;
    return 0.5f * x * (1.0f + tanhf(0.7978845608028654f * (x + 0.044715f * x3)));
}

// W[j][c] = scale * sum_e w_q[e][j] * w_k[e][c]   (scale = 256^-0.5 = 1/16)
__global__ void k_prep(const float* __restrict__ w_q, const float* __restrict__ w_k,
                       float* __restrict__ W) {
    const int j = blockIdx.x;
    const int c = threadIdx.x;
    float acc = 0.f;
    for (int e = 0; e < EDIM; ++e)
        acc += w_q[e * EDIM + j] * w_k[e * EDIM + c];
    W[j * EDIM + c] = acc * 0.0625f;
}

// qn = LN(qsrc_row); qpk[row][c] = sum_j qn[j] * W[j][c]
__global__ void k_qproj(const float* __restrict__ qsrc, const float* __restrict__ g_q,
                        const float* __restrict__ b_q, const float* __restrict__ W,
                        float* __restrict__ qpk) {
    const int row = blockIdx.x;   // 0..511
    const int t = threadIdx.x;
    __shared__ float qn[EDIM];
    __shared__ float red[16];
    const float v = qsrc[(size_t)row * EDIM + t];
    float s = v, ss = v * v;
#pragma unroll
    for (int m = 1; m < 64; m <<= 1) { s += __shfl_xor(s, m); ss += __shfl_xor(ss, m); }
    const int wave = t >> 6, lane = t & 63;
    if (lane == 0) { red[wave] = s; red[8 + wave] = ss; }
    __syncthreads();
    const float st = red[0] + red[1] + red[2] + red[3];
    const float sst = red[8] + red[9] + red[10] + red[11];
    const float mean = st * (1.0f / EDIM);
    const float rstd = rsqrtf(sst * (1.0f / EDIM) - mean * mean + EPS_LN);
    qn[t] = (v - mean) * rstd * g_q[t] + b_q[t];
    __syncthreads();
    float acc = 0.f;
    for (int j = 0; j < EDIM; ++j)
        acc += qn[j] * W[j * EDIM + t];
    qpk[(size_t)row * EDIM + t] = acc;
}

// One streaming pass over input: LN row -> logits (16) -> softmax over slots ->
// accumulate sum_attn and sum(attn * kvn) into per-block partials.
template <bool LAST>
__global__ __launch_bounds__(256, 2) void k_bigpass(
    const float* __restrict__ input, const float* __restrict__ g_kv,
    const float* __restrict__ b_kv, const float* __restrict__ qpk,
    float* __restrict__ pacc, float* __restrict__ psum, float* __restrict__ attn_out) {
    const int b = blockIdx.x / BPB;
    const int blk = blockIdx.x % BPB;
    const int wave = threadIdx.x >> 6;
    const int lane = threadIdx.x & 63;
    const int c0 = lane << 2;

    __shared__ __align__(16) float combine[NS * EDIM];   // 16 KB
    __shared__ __align__(16) float attn_lds[NS * RPB];   // 16 KB
    __shared__ float psum_lds[4][NS];

    float qr[NS][4];
#pragma unroll
    for (int s = 0; s < NS; ++s) {
        const float4 q4 = *reinterpret_cast<const float4*>(qpk + (size_t)(b * NS + s) * EDIM + c0);
        qr[s][0] = q4.x; qr[s][1] = q4.y; qr[s][2] = q4.z; qr[s][3] = q4.w;
    }
    const float4 g4 = *reinterpret_cast<const float4*>(g_kv + c0);
    const float4 bb4 = *reinterpret_cast<const float4*>(b_kv + c0);

    float acc[NS][4];
    float sumattn[NS];
#pragma unroll
    for (int s = 0; s < NS; ++s) {
        acc[s][0] = acc[s][1] = acc[s][2] = acc[s][3] = 0.f;
        sumattn[s] = 0.f;
    }

    const size_t rowbase = (size_t)b * HW + blk * RPB + wave * 64;
#pragma unroll 1
    for (int r = 0; r < 64; ++r) {
        const float4 x = *reinterpret_cast<const float4*>(input + (rowbase + r) * EDIM + c0);
        float s1 = x.x + x.y + x.z + x.w;
        float s2 = x.x * x.x + x.y * x.y + x.z * x.z + x.w * x.w;
#pragma unroll
        for (int m = 1; m < 64; m <<= 1) { s1 += __shfl_xor(s1, m); s2 += __shfl_xor(s2, m); }
        const float mean = s1 * (1.0f / EDIM);
        const float rstd = rsqrtf(s2 * (1.0f / EDIM) - mean * mean + EPS_LN);
        const float k0 = (x.x - mean) * rstd * g4.x + bb4.x;
        const float k1 = (x.y - mean) * rstd * g4.y + bb4.y;
        const float k2 = (x.z - mean) * rstd * g4.z + bb4.z;
        const float k3 = (x.w - mean) * rstd * g4.w + bb4.w;

        float p[NS];
#pragma unroll
        for (int s = 0; s < NS; ++s)
            p[s] = k0 * qr[s][0] + k1 * qr[s][1] + k2 * qr[s][2] + k3 * qr[s][3];
#pragma unroll
        for (int m = 1; m < 64; m <<= 1) {
#pragma unroll
            for (int s = 0; s < NS; ++s) p[s] += __shfl_xor(p[s], m);
        }
        float mx = p[0];
#pragma unroll
        for (int s = 1; s < NS; ++s) mx = fmaxf(mx, p[s]);
        float tot = 0.f;
#pragma unroll
        for (int s = 0; s < NS; ++s) { p[s] = __expf(p[s] - mx); tot += p[s]; }
        const float inv = 1.0f / tot;
#pragma unroll
        for (int s = 0; s < NS; ++s) {
            p[s] *= inv;
            sumattn[s] += p[s];
            acc[s][0] += p[s] * k0;
            acc[s][1] += p[s] * k1;
            acc[s][2] += p[s] * k2;
            acc[s][3] += p[s] * k3;
        }
        if (LAST) {
            if (lane == 0) {
                const int rib = wave * 64 + r;
#pragma unroll
                for (int s = 0; s < NS; ++s) attn_lds[s * RPB + rib] = p[s];
            }
        }
    }

    // deterministic cross-wave combine (wave order 0..3)
    for (int w = 0; w < 4; ++w) {
        __syncthreads();
        if (wave == w) {
#pragma unroll
            for (int s = 0; s < NS; ++s) {
                float4* dst = reinterpret_cast<float4*>(&combine[s * EDIM + c0]);
                if (w == 0) {
                    *dst = make_float4(acc[s][0], acc[s][1], acc[s][2], acc[s][3]);
                } else {
                    float4 tmp = *dst;
                    tmp.x += acc[s][0]; tmp.y += acc[s][1];
                    tmp.z += acc[s][2]; tmp.w += acc[s][3];
                    *dst = tmp;
                }
            }
        }
    }
    if (lane == 0) {
#pragma unroll
        for (int s = 0; s < NS; ++s) psum_lds[wave][s] = sumattn[s];
    }
    __syncthreads();

    const int t = threadIdx.x;
    const size_t pb = (size_t)(b * BPB + blk) * NS * EDIM;
#pragma unroll 1
    for (int s = 0; s < NS; ++s)
        pacc[pb + s * EDIM + t] = combine[s * EDIM + t];
    if (t < NS)
        psum[(b * BPB + blk) * NS + t] =
            psum_lds[0][t] + psum_lds[1][t] + psum_lds[2][t] + psum_lds[3][t];
    if (LAST) {
#pragma unroll 1
        for (int s = 0; s < NS; ++s)
            attn_out[(size_t)(b * NS + s) * HW + blk * RPB + t] = attn_lds[s * RPB + t];
    }
}

// Per-b: reduce partials, divide by (sum_attn + eps), project through w_v.T.
__global__ void k_mid(const float* __restrict__ pacc, const float* __restrict__ psum,
                      const float* __restrict__ w_v, float* __restrict__ updates) {
    const int b = blockIdx.x;
    const int t = threadIdx.x;
    __shared__ float denom[NS];
    __shared__ float ub[NS * EDIM];
    if (t < NS) {
        float d = 0.f;
        for (int w = 0; w < BPB; ++w) d += psum[(b * BPB + w) * NS + t];
        denom[t] = d + EPS_ATTN;
    }
    __syncthreads();
#pragma unroll 1
    for (int s = 0; s < NS; ++s) {
        float a = 0.f;
        for (int w = 0; w < BPB; ++w)
            a += pacc[(size_t)((b * BPB + w) * NS + s) * EDIM + t];
        ub[s * EDIM + t] = a / denom[s];
    }
    __syncthreads();
    float ua[NS];
#pragma unroll
    for (int s = 0; s < NS; ++s) ua[s] = 0.f;
    for (int c = 0; c < EDIM; ++c) {
        const float wv = w_v[(size_t)t * EDIM + c];
#pragma unroll
        for (int s = 0; s < NS; ++s) ua[s] += ub[s * EDIM + c] * wv;
    }
#pragma unroll
    for (int s = 0; s < NS; ++s)
        updates[(size_t)(b * NS + s) * EDIM + t] = ua[s];
}

// Row-parallel GRU + LN + FFN chain. 128 blocks x 4 rows each.
__global__ __launch_bounds__(256) void k_chain(
    const float* __restrict__ updates, const float* __restrict__ qsrc,
    const float* __restrict__ w_ih, const float* __restrict__ w_hh,
    const float* __restrict__ b_ih, const float* __restrict__ b_hh,
    const float* __restrict__ g_2, const float* __restrict__ b_2,
    const float* __restrict__ w_f1, const float* __restrict__ b_f1,
    const float* __restrict__ w_f2, const float* __restrict__ b_f2,
    const float* __restrict__ query, float* __restrict__ q_out, int adjust) {
    const int bid = blockIdx.x;
    const int b = bid >> 2;
    const int sg = bid & 3;
    const int row0 = b * NS + sg * 4;
    const int t = threadIdx.x;

    __shared__ __align__(16) float upd[4][EDIM];
    __shared__ __align__(16) float qrow[4][EDIM];
    __shared__ __align__(16) float gi[4][3 * EDIM];
    __shared__ __align__(16) float gh[4][3 * EDIM];
    __shared__ __align__(16) float slots[4][EDIM];
    __shared__ __align__(16) float ln2[4][EDIM];
    __shared__ __align__(16) float h1[4][FFND];

#pragma unroll
    for (int r = 0; r < 4; ++r) {
        upd[r][t] = updates[(size_t)(row0 + r) * EDIM + t];
        qrow[r][t] = qsrc[(size_t)(row0 + r) * EDIM + t];
    }
    __syncthreads();

    {   // gi = upd @ w_ih.T + b_ih ; gh = qrow @ w_hh.T + b_hh
        float accI[3][4], accH[3][4];
#pragma unroll
        for (int k = 0; k < 3; ++k)
#pragma unroll
            for (int r = 0; r < 4; ++r) { accI[k][r] = 0.f; accH[k][r] = 0.f; }
        for (int j = 0; j < EDIM; j += 4) {
            float4 u[4], qv[4];
#pragma unroll
            for (int r = 0; r < 4; ++r) {
                u[r] = *reinterpret_cast<const float4*>(&upd[r][j]);
                qv[r] = *reinterpret_cast<const float4*>(&qrow[r][j]);
            }
#pragma unroll
            for (int k = 0; k < 3; ++k) {
                const float4 wi = *reinterpret_cast<const float4*>(&w_ih[(size_t)(k * EDIM + t) * EDIM + j]);
                const float4 wh = *reinterpret_cast<const float4*>(&w_hh[(size_t)(k * EDIM + t) * EDIM + j]);
#pragma unroll
                for (int r = 0; r < 4; ++r) {
                    accI[k][r] += u[r].x * wi.x + u[r].y * wi.y + u[r].z * wi.z + u[r].w * wi.w;
                    accH[k][r] += qv[r].x * wh.x + qv[r].y * wh.y + qv[r].z * wh.z + qv[r].w * wh.w;
                }
            }
        }
#pragma unroll
        for (int k = 0; k < 3; ++k) {
            const float bi = b_ih[k * EDIM + t];
            const float bh = b_hh[k * EDIM + t];
#pragma unroll
            for (int r = 0; r < 4; ++r) {
                gi[r][k * EDIM + t] = accI[k][r] + bi;
                gh[r][k * EDIM + t] = accH[k][r] + bh;
            }
        }
    }
    __syncthreads();

#pragma unroll
    for (int r = 0; r < 4; ++r) {   // GRU gates
        const float ir = gi[r][t], iz = gi[r][EDIM + t], inn = gi[r][2 * EDIM + t];
        const float hr = gh[r][t], hz = gh[r][EDIM + t], hn = gh[r][2 * EDIM + t];
        const float h = qrow[r][t];
        const float rg = sigmoidf_(ir + hr);
        const float z = sigmoidf_(iz + hz);
        const float n = tanhf(inn + rg * hn);
        slots[r][t] = (1.0f - z) * n + z * h;
    }
    __syncthreads();

    {   // LN(slots) per row: one wave per row
        const int wv = t >> 6, ln = t & 63;
        const float4 v = *reinterpret_cast<const float4*>(&slots[wv][ln * 4]);
        float s1 = v.x + v.y + v.z + v.w;
        float s2 = v.x * v.x + v.y * v.y + v.z * v.z + v.w * v.w;
#pragma unroll
        for (int m = 1; m < 64; m <<= 1) { s1 += __shfl_xor(s1, m); s2 += __shfl_xor(s2, m); }
        const float mean = s1 * (1.0f / EDIM);
        const float rstd = rsqrtf(s2 * (1.0f / EDIM) - mean * mean + EPS_LN);
        const float4 gg = *reinterpret_cast<const float4*>(g_2 + ln * 4);
        const float4 bb = *reinterpret_cast<const float4*>(b_2 + ln * 4);
        float4 o;
        o.x = (v.x - mean) * rstd * gg.x + bb.x;
        o.y = (v.y - mean) * rstd * gg.y + bb.y;
        o.z = (v.z - mean) * rstd * gg.z + bb.z;
        o.w = (v.w - mean) * rstd * gg.w + bb.w;
        *reinterpret_cast<float4*>(&ln2[wv][ln * 4]) = o;
    }
    __syncthreads();

    {   // h1 = gelu(ln2 @ w_f1.T + b_f1)
        float acc[4][4];
#pragma unroll
        for (int k = 0; k < 4; ++k)
#pragma unroll
            for (int r = 0; r < 4; ++r) acc[k][r] = 0.f;
        for (int j = 0; j < EDIM; j += 4) {
            float4 l[4];
#pragma unroll
            for (int r = 0; r < 4; ++r) l[r] = *reinterpret_cast<const float4*>(&ln2[r][j]);
#pragma unroll
            for (int k = 0; k < 4; ++k) {
                const float4 w = *reinterpret_cast<const float4*>(&w_f1[(size_t)(k * EDIM + t) * EDIM + j]);
#pragma unroll
                for (int r = 0; r < 4; ++r)
                    acc[k][r] += l[r].x * w.x + l[r].y * w.y + l[r].z * w.z + l[r].w * w.w;
            }
        }
#pragma unroll
        for (int k = 0; k < 4; ++k) {
            const float bf = b_f1[k * EDIM + t];
#pragma unroll
            for (int r = 0; r < 4; ++r) h1[r][k * EDIM + t] = gelu_(acc[k][r] + bf);
        }
    }
    __syncthreads();

    {   // q = slots + h1 @ w_f2.T + b_f2  (+ optional stop-grad forward identity)
        float acc[4] = {0.f, 0.f, 0.f, 0.f};
        for (int j = 0; j < FFND; j += 4) {
            const float4 w = *reinterpret_cast<const float4*>(&w_f2[(size_t)t * FFND + j]);
#pragma unroll
            for (int r = 0; r < 4; ++r) {
                const float4 hh = *reinterpret_cast<const float4*>(&h1[r][j]);
                acc[r] += hh.x * w.x + hh.y * w.y + hh.z * w.z + hh.w * w.w;
            }
        }
        const float bf = b_f2[t];
#pragma unroll
        for (int r = 0; r < 4; ++r) {
            float qn = slots[r][t] + acc[r] + bf;
            if (adjust) {
                const float qq = query[(size_t)(row0 + r) * EDIM + t];
                qn = (qn + qq) - qq;   // replicate (sg(q)+query)-sg(query) forward rounding
            }
            q_out[(size_t)(row0 + r) * EDIM + t] = qn;
        }
    }
}

extern "C" void kernel_launch(void* const* d_in, const int* in_sizes, int n_in,
                              void* d_out, int out_size, void* d_ws, size_t ws_size,
                              hipStream_t stream) {
    const float* input = (const float*)d_in[0];
    const float* query = (const float*)d_in[1];
    const float* g_kv = (const float*)d_in[2];
    const float* b_kv = (const float*)d_in[3];
    const float* w_k = (const float*)d_in[4];
    const float* w_v = (const float*)d_in[5];
    const float* g_q = (const float*)d_in[6];
    const float* b_q = (const float*)d_in[7];
    const float* w_q = (const float*)d_in[8];
    const float* w_ih = (const float*)d_in[9];
    const float* w_hh = (const float*)d_in[10];
    const float* b_ih = (const float*)d_in[11];
    const float* b_hh = (const float*)d_in[12];
    const float* g_2 = (const float*)d_in[13];
    const float* b_2 = (const float*)d_in[14];
    const float* w_f1 = (const float*)d_in[15];
    const float* b_f1 = (const float*)d_in[16];
    const float* w_f2 = (const float*)d_in[17];
    const float* b_f2 = (const float*)d_in[18];

    float* ws = (float*)d_ws;
    float* W = ws;        ws += 256 * 256;
    float* qpk = ws;      ws += 512 * 256;
    float* pacc = ws;     ws += (size_t)NB * BPB * NS * EDIM;   // 512*16*256
    float* psum = ws;     ws += NB * BPB * NS;
    float* updates = ws;  ws += 512 * 256;
    float* q_ws = ws;     ws += 512 * 256;

    float* out_q = (float*)d_out;
    float* out_attn = out_q + (size_t)NB * NS * EDIM;

    k_prep<<<256, 256, 0, stream>>>(w_q, w_k, W);

    // ---- iteration 0 (q = query) ----
    k_qproj<<<512, 256, 0, stream>>>(query, g_q, b_q, W, qpk);
    k_bigpass<false><<<NB * BPB, 256, 0, stream>>>(input, g_kv, b_kv, qpk, pacc, psum, nullptr);
    k_mid<<<NB, 256, 0, stream>>>(pacc, psum, w_v, updates);
    k_chain<<<128, 256, 0, stream>>>(updates, query, w_ih, w_hh, b_ih, b_hh, g_2, b_2,
                                     w_f1, b_f1, w_f2, b_f2, query, q_ws, 0);

    // ---- iteration 1 (adjust q at the end for bi-level trick of iter 2) ----
    k_qproj<<<512, 256, 0, stream>>>(q_ws, g_q, b_q, W, qpk);
    k_bigpass<false><<<NB * BPB, 256, 0, stream>>>(input, g_kv, b_kv, qpk, pacc, psum, nullptr);
    k_mid<<<NB, 256, 0, stream>>>(pacc, psum, w_v, updates);
    k_chain<<<128, 256, 0, stream>>>(updates, q_ws, w_ih, w_hh, b_ih, b_hh, g_2, b_2,
                                     w_f1, b_f1, w_f2, b_f2, query, q_ws, 1);

    // ---- iteration 2 (LAST: write attn; q goes straight to d_out) ----
    k_qproj<<<512, 256, 0, stream>>>(q_ws, g_q, b_q, W, qpk);
    k_bigpass<true><<<NB * BPB, 256, 0, stream>>>(input, g_kv, b_kv, qpk, pacc, psum, out_attn);
    k_mid<<<NB, 256, 0, stream>>>(pacc, psum, w_v, updates);
    k_chain<<<128, 256, 0, stream>>>(updates, q_ws, w_ih, w_hh, b_ih, b_hh, g_2, b_2,
                                     w_f1, b_f1, w_f2, b_f2, query, out_q, 0);
}

// Round 3
// 942.979 us; speedup vs baseline: 1.1325x; 1.1325x over previous
//
#include <hip/hip_runtime.h>
#include <math.h>

#define NB 32
#define HW 4096
#define NS 16
#define EDIM 256
#define FFND 1024
#define EPS_LN 1e-5f
#define EPS_ATTN 1e-5f
#define BPB 16           // blocks per batch in bigpass
#define RPB (HW / BPB)   // 256 rows per block

__device__ __forceinline__ float sigmoidf_(float x) { return 1.0f / (1.0f + __expf(-x)); }
__device__ __forceinline__ float gelu_(float x) {
    float x3 = x * x * x;
    return 0.5f * x * (1.0f + tanhf(0.7978845608028654f * (x + 0.044715f * x3)));
}

// W[j][c] = scale * sum_e w_q[e][j] * w_k[e][c]   (scale = 256^-0.5 = 1/16)
__global__ void k_prep(const float* __restrict__ w_q, const float* __restrict__ w_k,
                       float* __restrict__ W) {
    const int j = blockIdx.x;
    const int c = threadIdx.x;
    float acc = 0.f;
    for (int e = 0; e < EDIM; ++e)
        acc += w_q[e * EDIM + j] * w_k[e * EDIM + c];
    W[j * EDIM + c] = acc * 0.0625f;
}

// qn = LN(qsrc_row); qpk[row][c] = sum_j qn[j] * W[j][c]
// also gq[b][s] = sum_c g_kv[c]*qpk, bq[b][s] = sum_c b_kv[c]*qpk
__global__ void k_qproj(const float* __restrict__ qsrc, const float* __restrict__ g_q,
                        const float* __restrict__ b_q, const float* __restrict__ W,
                        const float* __restrict__ g_kv, const float* __restrict__ b_kv,
                        float* __restrict__ qpk, float* __restrict__ gqbq) {
    const int row = blockIdx.x;   // 0..511  (= b*16 + s)
    const int t = threadIdx.x;
    __shared__ float qn[EDIM];
    __shared__ float red[16];
    const float v = qsrc[(size_t)row * EDIM + t];
    float s = v, ss = v * v;
#pragma unroll
    for (int m = 1; m < 64; m <<= 1) { s += __shfl_xor(s, m); ss += __shfl_xor(ss, m); }
    const int wave = t >> 6, lane = t & 63;
    if (lane == 0) { red[wave] = s; red[8 + wave] = ss; }
    __syncthreads();
    const float st = red[0] + red[1] + red[2] + red[3];
    const float sst = red[8] + red[9] + red[10] + red[11];
    const float mean = st * (1.0f / EDIM);
    const float rstd = rsqrtf(sst * (1.0f / EDIM) - mean * mean + EPS_LN);
    qn[t] = (v - mean) * rstd * g_q[t] + b_q[t];
    __syncthreads();
    float acc = 0.f;
    for (int j = 0; j < EDIM; ++j)
        acc += qn[j] * W[j * EDIM + t];
    qpk[(size_t)row * EDIM + t] = acc;
    // gq/bq reductions
    float u = acc * g_kv[t];
    float w2 = acc * b_kv[t];
#pragma unroll
    for (int m = 1; m < 64; m <<= 1) { u += __shfl_xor(u, m); w2 += __shfl_xor(w2, m); }
    __syncthreads();
    if (lane == 0) { red[wave] = u; red[8 + wave] = w2; }
    __syncthreads();
    if (t == 0) {
        const int b = row >> 4, sl = row & 15;
        gqbq[b * 32 + sl] = red[0] + red[1] + red[2] + red[3];
        gqbq[b * 32 + 16 + sl] = red[8] + red[9] + red[10] + red[11];
    }
}

// Streaming pass: per wave-owned 16-row tile:
// phase A (4 lanes/row): dot(x, G[s]) + LN stats -> 2-step shfl -> softmax -> wrec
// phase B (lane=channel-quad): V[s][c] += (attn*rstd)*x[c]  (rank-16 accumulate)
template <bool LAST>
__global__ __launch_bounds__(256, 2) void k_bigpass(
    const float* __restrict__ input, const float* __restrict__ qpk,
    const float* __restrict__ gqbq, const float* __restrict__ g_kv,
    float* __restrict__ pacc, float* __restrict__ psum, float* __restrict__ attn_out) {
    const int b = blockIdx.x >> 4;
    const int sub = blockIdx.x & 15;
    const int t = threadIdx.x;
    const int wave = t >> 6;
    const int lane = t & 63;
    const int g = lane >> 2;   // row in tile (0..15)
    const int j = lane & 3;    // channel interleave

    __shared__ __align__(16) float G[NS][EDIM];        // g_kv * qpk; reused as combine buf
    __shared__ __align__(16) float wrec[4][16][20];    // per wave: attn[16], rstd, rstd*mean
    __shared__ float gqbq_s[2][NS];
    __shared__ float exS[4][NS];
    __shared__ float exA[4][NS];
    __shared__ __align__(16) float attn_lds[NS][RPB];  // only used when LAST

    // prologue: G = g_kv (broadcast over s) * qpk[b]
#pragma unroll
    for (int i = 0; i < 4; ++i) {
        const int idx = i * 1024 + t * 4;
        const float4 qv = *reinterpret_cast<const float4*>(qpk + (size_t)b * 4096 + idx);
        const float4 gv = *reinterpret_cast<const float4*>(g_kv + (idx & 255));
        *reinterpret_cast<float4*>(&G[0][0] + idx) =
            make_float4(qv.x * gv.x, qv.y * gv.y, qv.z * gv.z, qv.w * gv.w);
    }
    if (t < 32) gqbq_s[t >> 4][t & 15] = gqbq[b * 32 + t];
    __syncthreads();

    float acc[NS][4];
    float extra[NS];
#pragma unroll
    for (int s = 0; s < NS; ++s) {
        acc[s][0] = acc[s][1] = acc[s][2] = acc[s][3] = 0.f;
        extra[s] = 0.f;
    }

    const int row0b = sub * RPB;
#pragma unroll 1
    for (int tt = 0; tt < 4; ++tt) {
        const int r0 = row0b + wave * 64 + tt * 16;
        const int row = r0 + g;
        const float* xr = input + ((size_t)b * HW + row) * EDIM;

        // ---- phase A ----
        float p[NS];
#pragma unroll
        for (int s = 0; s < NS; ++s) p[s] = 0.f;
        float s1 = 0.f, s2 = 0.f;
#pragma unroll
        for (int q = 0; q < 16; ++q) {
            const float4 x = *reinterpret_cast<const float4*>(xr + q * 16 + j * 4);
            s1 += x.x + x.y + x.z + x.w;
            s2 += x.x * x.x + x.y * x.y + x.z * x.z + x.w * x.w;
#pragma unroll
            for (int s = 0; s < NS; ++s) {
                const float4 gg = *reinterpret_cast<const float4*>(&G[s][q * 16 + j * 4]);
                p[s] += x.x * gg.x + x.y * gg.y + x.z * gg.z + x.w * gg.w;
            }
        }
#pragma unroll
        for (int m = 1; m < 4; m <<= 1) {
            s1 += __shfl_xor(s1, m);
            s2 += __shfl_xor(s2, m);
#pragma unroll
            for (int s = 0; s < NS; ++s) p[s] += __shfl_xor(p[s], m);
        }
        const float mean = s1 * (1.0f / EDIM);
        const float rstd = rsqrtf(s2 * (1.0f / EDIM) - mean * mean + EPS_LN);
        float mx = -1e30f;
#pragma unroll
        for (int s = 0; s < NS; ++s) {
            p[s] = rstd * (p[s] - mean * gqbq_s[0][s]) + gqbq_s[1][s];
            mx = fmaxf(mx, p[s]);
        }
        float tot = 0.f;
#pragma unroll
        for (int s = 0; s < NS; ++s) { p[s] = __expf(p[s] - mx); tot += p[s]; }
        const float inv = 1.0f / tot;
        // S (j==0) and A (j==1) partials; other lanes contribute 0
        const float coef = (j == 0) ? inv : ((j == 1) ? inv * rstd * mean : 0.f);
#pragma unroll
        for (int s = 0; s < NS; ++s) extra[s] += p[s] * coef;
        if (j == 0) {
#pragma unroll
            for (int sq = 0; sq < 4; ++sq)
                *reinterpret_cast<float4*>(&wrec[wave][g][sq * 4]) =
                    make_float4(p[sq * 4 + 0] * inv, p[sq * 4 + 1] * inv,
                                p[sq * 4 + 2] * inv, p[sq * 4 + 3] * inv);
            wrec[wave][g][16] = rstd;
            wrec[wave][g][17] = rstd * mean;
            if (LAST) {
                const int lr = row - row0b;
#pragma unroll
                for (int s = 0; s < NS; ++s) attn_lds[s][lr] = p[s] * inv;
            }
        }
        // make wrec writes visible to all lanes of this wave before phase B reads
        asm volatile("s_waitcnt lgkmcnt(0)" ::: "memory");
        __builtin_amdgcn_sched_barrier(0);

        // ---- phase B ----
        const float* xb = input + ((size_t)b * HW + r0) * EDIM + lane * 4;
#pragma unroll
        for (int r = 0; r < 16; ++r) {
            const float4 x = *reinterpret_cast<const float4*>(xb + (size_t)r * EDIM);
            const float lrstd = wrec[wave][r][16];
#pragma unroll
            for (int sq = 0; sq < 4; ++sq) {
                const float4 aq = *reinterpret_cast<const float4*>(&wrec[wave][r][sq * 4]);
                float w;
                w = aq.x * lrstd;
                acc[sq * 4 + 0][0] += w * x.x; acc[sq * 4 + 0][1] += w * x.y;
                acc[sq * 4 + 0][2] += w * x.z; acc[sq * 4 + 0][3] += w * x.w;
                w = aq.y * lrstd;
                acc[sq * 4 + 1][0] += w * x.x; acc[sq * 4 + 1][1] += w * x.y;
                acc[sq * 4 + 1][2] += w * x.z; acc[sq * 4 + 1][3] += w * x.w;
                w = aq.z * lrstd;
                acc[sq * 4 + 2][0] += w * x.x; acc[sq * 4 + 2][1] += w * x.y;
                acc[sq * 4 + 2][2] += w * x.z; acc[sq * 4 + 2][3] += w * x.w;
                w = aq.w * lrstd;
                acc[sq * 4 + 3][0] += w * x.x; acc[sq * 4 + 3][1] += w * x.y;
                acc[sq * 4 + 3][2] += w * x.z; acc[sq * 4 + 3][3] += w * x.w;
            }
        }
    }

    // reduce extra over lanes with same j (masks 4..32): j==0 -> S, j==1 -> A
#pragma unroll
    for (int m = 4; m < 64; m <<= 1) {
#pragma unroll
        for (int s = 0; s < NS; ++s) extra[s] += __shfl_xor(extra[s], m);
    }
    if (lane == 0) {
#pragma unroll
        for (int s = 0; s < NS; ++s) exS[wave][s] = extra[s];
    }
    if (lane == 1) {
#pragma unroll
        for (int s = 0; s < NS; ++s) exA[wave][s] = extra[s];
    }

    // cross-wave combine of acc into G (deterministic wave order)
    for (int w = 0; w < 4; ++w) {
        __syncthreads();
        if (wave == w) {
#pragma unroll
            for (int s = 0; s < NS; ++s) {
                float4* dst = reinterpret_cast<float4*>(&G[s][lane * 4]);
                if (w == 0) {
                    *dst = make_float4(acc[s][0], acc[s][1], acc[s][2], acc[s][3]);
                } else {
                    float4 tmp = *dst;
                    tmp.x += acc[s][0]; tmp.y += acc[s][1];
                    tmp.z += acc[s][2]; tmp.w += acc[s][3];
                    *dst = tmp;
                }
            }
        }
    }
    __syncthreads();

    const size_t pb = (size_t)blockIdx.x * NS * EDIM;
#pragma unroll 1
    for (int s = 0; s < NS; ++s)
        pacc[pb + s * EDIM + t] = G[s][t];
    if (t < NS) {
        psum[blockIdx.x * 32 + t] = exS[0][t] + exS[1][t] + exS[2][t] + exS[3][t];
        psum[blockIdx.x * 32 + 16 + t] = exA[0][t] + exA[1][t] + exA[2][t] + exA[3][t];
    }
    if (LAST) {
#pragma unroll 1
        for (int s = 0; s < NS; ++s)
            attn_out[((size_t)b * NS + s) * HW + row0b + t] = attn_lds[s][t];
    }
}

// block = (b, slot): reduce partials, apply g/b fold + denom, project through w_v.T
__global__ void k_mid(const float* __restrict__ pacc, const float* __restrict__ psum,
                      const float* __restrict__ w_v, const float* __restrict__ g_kv,
                      const float* __restrict__ b_kv, float* __restrict__ updates) {
    const int b = blockIdx.x >> 4;
    const int s = blockIdx.x & 15;
    const int t = threadIdx.x;
    __shared__ float ub[EDIM];
    __shared__ float sred[2];
    if (t == 0) {
        float S = 0.f, A = 0.f;
        for (int p_ = 0; p_ < BPB; ++p_) {
            S += psum[(b * BPB + p_) * 32 + s];
            A += psum[(b * BPB + p_) * 32 + 16 + s];
        }
        sred[0] = S; sred[1] = A;
    }
    __syncthreads();
    const float S = sred[0], A = sred[1];
    float V = 0.f;
    for (int p_ = 0; p_ < BPB; ++p_)
        V += pacc[((size_t)(b * BPB + p_) * NS + s) * EDIM + t];
    ub[t] = (g_kv[t] * (V - A) + b_kv[t] * S) / (S + EPS_ATTN);
    __syncthreads();
    float acc = 0.f;
    for (int c = 0; c < EDIM; c += 4) {
        const float4 u = *reinterpret_cast<const float4*>(&ub[c]);
        const float4 w4 = *reinterpret_cast<const float4*>(w_v + (size_t)t * EDIM + c);
        acc += u.x * w4.x + u.y * w4.y + u.z * w4.z + u.w * w4.w;
    }
    updates[((size_t)b * NS + s) * EDIM + t] = acc;
}

// Row-parallel GRU + LN + FFN chain. 128 blocks x 4 rows each.
__global__ __launch_bounds__(256) void k_chain(
    const float* __restrict__ updates, const float* __restrict__ qsrc,
    const float* __restrict__ w_ih, const float* __restrict__ w_hh,
    const float* __restrict__ b_ih, const float* __restrict__ b_hh,
    const float* __restrict__ g_2, const float* __restrict__ b_2,
    const float* __restrict__ w_f1, const float* __restrict__ b_f1,
    const float* __restrict__ w_f2, const float* __restrict__ b_f2,
    const float* __restrict__ query, float* __restrict__ q_out, int adjust) {
    const int bid = blockIdx.x;
    const int b = bid >> 2;
    const int sg = bid & 3;
    const int row0 = b * NS + sg * 4;
    const int t = threadIdx.x;

    __shared__ __align__(16) float upd[4][EDIM];
    __shared__ __align__(16) float qrow[4][EDIM];
    __shared__ __align__(16) float gi[4][3 * EDIM];
    __shared__ __align__(16) float gh[4][3 * EDIM];
    __shared__ __align__(16) float slots[4][EDIM];
    __shared__ __align__(16) float ln2[4][EDIM];
    __shared__ __align__(16) float h1[4][FFND];

#pragma unroll
    for (int r = 0; r < 4; ++r) {
        upd[r][t] = updates[(size_t)(row0 + r) * EDIM + t];
        qrow[r][t] = qsrc[(size_t)(row0 + r) * EDIM + t];
    }
    __syncthreads();

    {   // gi = upd @ w_ih.T + b_ih ; gh = qrow @ w_hh.T + b_hh
        float accI[3][4], accH[3][4];
#pragma unroll
        for (int k = 0; k < 3; ++k)
#pragma unroll
            for (int r = 0; r < 4; ++r) { accI[k][r] = 0.f; accH[k][r] = 0.f; }
        for (int j = 0; j < EDIM; j += 4) {
            float4 u[4], qv[4];
#pragma unroll
            for (int r = 0; r < 4; ++r) {
                u[r] = *reinterpret_cast<const float4*>(&upd[r][j]);
                qv[r] = *reinterpret_cast<const float4*>(&qrow[r][j]);
            }
#pragma unroll
            for (int k = 0; k < 3; ++k) {
                const float4 wi = *reinterpret_cast<const float4*>(&w_ih[(size_t)(k * EDIM + t) * EDIM + j]);
                const float4 wh = *reinterpret_cast<const float4*>(&w_hh[(size_t)(k * EDIM + t) * EDIM + j]);
#pragma unroll
                for (int r = 0; r < 4; ++r) {
                    accI[k][r] += u[r].x * wi.x + u[r].y * wi.y + u[r].z * wi.z + u[r].w * wi.w;
                    accH[k][r] += qv[r].x * wh.x + qv[r].y * wh.y + qv[r].z * wh.z + qv[r].w * wh.w;
                }
            }
        }
#pragma unroll
        for (int k = 0; k < 3; ++k) {
            const float bi = b_ih[k * EDIM + t];
            const float bh = b_hh[k * EDIM + t];
#pragma unroll
            for (int r = 0; r < 4; ++r) {
                gi[r][k * EDIM + t] = accI[k][r] + bi;
                gh[r][k * EDIM + t] = accH[k][r] + bh;
            }
        }
    }
    __syncthreads();

#pragma unroll
    for (int r = 0; r < 4; ++r) {   // GRU gates
        const float ir = gi[r][t], iz = gi[r][EDIM + t], inn = gi[r][2 * EDIM + t];
        const float hr = gh[r][t], hz = gh[r][EDIM + t], hn = gh[r][2 * EDIM + t];
        const float h = qrow[r][t];
        const float rg = sigmoidf_(ir + hr);
        const float z = sigmoidf_(iz + hz);
        const float n = tanhf(inn + rg * hn);
        slots[r][t] = (1.0f - z) * n + z * h;
    }
    __syncthreads();

    {   // LN(slots) per row: one wave per row
        const int wv = t >> 6, ln = t & 63;
        const float4 v = *reinterpret_cast<const float4*>(&slots[wv][ln * 4]);
        float s1 = v.x + v.y + v.z + v.w;
        float s2 = v.x * v.x + v.y * v.y + v.z * v.z + v.w * v.w;
#pragma unroll
        for (int m = 1; m < 64; m <<= 1) { s1 += __shfl_xor(s1, m); s2 += __shfl_xor(s2, m); }
        const float mean = s1 * (1.0f / EDIM);
        const float rstd = rsqrtf(s2 * (1.0f / EDIM) - mean * mean + EPS_LN);
        const float4 gg = *reinterpret_cast<const float4*>(g_2 + ln * 4);
        const float4 bb = *reinterpret_cast<const float4*>(b_2 + ln * 4);
        float4 o;
        o.x = (v.x - mean) * rstd * gg.x + bb.x;
        o.y = (v.y - mean) * rstd * gg.y + bb.y;
        o.z = (v.z - mean) * rstd * gg.z + bb.z;
        o.w = (v.w - mean) * rstd * gg.w + bb.w;
        *reinterpret_cast<float4*>(&ln2[wv][ln * 4]) = o;
    }
    __syncthreads();

    {   // h1 = gelu(ln2 @ w_f1.T + b_f1)
        float acc[4][4];
#pragma unroll
        for (int k = 0; k < 4; ++k)
#pragma unroll
            for (int r = 0; r < 4; ++r) acc[k][r] = 0.f;
        for (int j = 0; j < EDIM; j += 4) {
            float4 l[4];
#pragma unroll
            for (int r = 0; r < 4; ++r) l[r] = *reinterpret_cast<const float4*>(&ln2[r][j]);
#pragma unroll
            for (int k = 0; k < 4; ++k) {
                const float4 w = *reinterpret_cast<const float4*>(&w_f1[(size_t)(k * EDIM + t) * EDIM + j]);
#pragma unroll
                for (int r = 0; r < 4; ++r)
                    acc[k][r] += l[r].x * w.x + l[r].y * w.y + l[r].z * w.z + l[r].w * w.w;
            }
        }
#pragma unroll
        for (int k = 0; k < 4; ++k) {
            const float bf = b_f1[k * EDIM + t];
#pragma unroll
            for (int r = 0; r < 4; ++r) h1[r][k * EDIM + t] = gelu_(acc[k][r] + bf);
        }
    }
    __syncthreads();

    {   // q = slots + h1 @ w_f2.T + b_f2  (+ optional stop-grad forward identity)
        float acc[4] = {0.f, 0.f, 0.f, 0.f};
        for (int j = 0; j < FFND; j += 4) {
            const float4 w = *reinterpret_cast<const float4*>(&w_f2[(size_t)t * FFND + j]);
#pragma unroll
            for (int r = 0; r < 4; ++r) {
                const float4 hh = *reinterpret_cast<const float4*>(&h1[r][j]);
                acc[r] += hh.x * w.x + hh.y * w.y + hh.z * w.z + hh.w * w.w;
            }
        }
        const float bf = b_f2[t];
#pragma unroll
        for (int r = 0; r < 4; ++r) {
            float qn = slots[r][t] + acc[r] + bf;
            if (adjust) {
                const float qq = query[(size_t)(row0 + r) * EDIM + t];
                qn = (qn + qq) - qq;   // replicate (sg(q)+query)-sg(query) forward rounding
            }
            q_out[(size_t)(row0 + r) * EDIM + t] = qn;
        }
    }
}

extern "C" void kernel_launch(void* const* d_in, const int* in_sizes, int n_in,
                              void* d_out, int out_size, void* d_ws, size_t ws_size,
                              hipStream_t stream) {
    const float* input = (const float*)d_in[0];
    const float* query = (const float*)d_in[1];
    const float* g_kv = (const float*)d_in[2];
    const float* b_kv = (const float*)d_in[3];
    const float* w_k = (const float*)d_in[4];
    const float* w_v = (const float*)d_in[5];
    const float* g_q = (const float*)d_in[6];
    const float* b_q = (const float*)d_in[7];
    const float* w_q = (const float*)d_in[8];
    const float* w_ih = (const float*)d_in[9];
    const float* w_hh = (const float*)d_in[10];
    const float* b_ih = (const float*)d_in[11];
    const float* b_hh = (const float*)d_in[12];
    const float* g_2 = (const float*)d_in[13];
    const float* b_2 = (const float*)d_in[14];
    const float* w_f1 = (const float*)d_in[15];
    const float* b_f1 = (const float*)d_in[16];
    const float* w_f2 = (const float*)d_in[17];
    const float* b_f2 = (const float*)d_in[18];

    float* ws = (float*)d_ws;
    float* W = ws;        ws += 256 * 256;
    float* qpk = ws;      ws += 512 * 256;
    float* gqbq = ws;     ws += NB * 32;
    float* pacc = ws;     ws += (size_t)NB * BPB * NS * EDIM;   // 512*16*256
    float* psum = ws;     ws += NB * BPB * 32;
    float* updates = ws;  ws += 512 * 256;
    float* q_ws = ws;     ws += 512 * 256;

    float* out_q = (float*)d_out;
    float* out_attn = out_q + (size_t)NB * NS * EDIM;

    k_prep<<<256, 256, 0, stream>>>(w_q, w_k, W);

    // ---- iteration 0 (q = query) ----
    k_qproj<<<512, 256, 0, stream>>>(query, g_q, b_q, W, g_kv, b_kv, qpk, gqbq);
    k_bigpass<false><<<NB * BPB, 256, 0, stream>>>(input, qpk, gqbq, g_kv, pacc, psum, nullptr);
    k_mid<<<NB * NS, 256, 0, stream>>>(pacc, psum, w_v, g_kv, b_kv, updates);
    k_chain<<<128, 256, 0, stream>>>(updates, query, w_ih, w_hh, b_ih, b_hh, g_2, b_2,
                                     w_f1, b_f1, w_f2, b_f2, query, q_ws, 0);

    // ---- iteration 1 (adjust q at the end for bi-level trick of iter 2) ----
    k_qproj<<<512, 256, 0, stream>>>(q_ws, g_q, b_q, W, g_kv, b_kv, qpk, gqbq);
    k_bigpass<false><<<NB * BPB, 256, 0, stream>>>(input, qpk, gqbq, g_kv, pacc, psum, nullptr);
    k_mid<<<NB * NS, 256, 0, stream>>>(pacc, psum, w_v, g_kv, b_kv, updates);
    k_chain<<<128, 256, 0, stream>>>(updates, q_ws, w_ih, w_hh, b_ih, b_hh, g_2, b_2,
                                     w_f1, b_f1, w_f2, b_f2, query, q_ws, 1);

    // ---- iteration 2 (LAST: write attn; q goes straight to d_out) ----
    k_qproj<<<512, 256, 0, stream>>>(q_ws, g_q, b_q, W, g_kv, b_kv, qpk, gqbq);
    k_bigpass<true><<<NB * BPB, 256, 0, stream>>>(input, qpk, gqbq, g_kv, pacc, psum, out_attn);
    k_mid<<<NB * NS, 256, 0, stream>>>(pacc, psum, w_v, g_kv, b_kv, updates);
    k_chain<<<128, 256, 0, stream>>>(updates, q_ws, w_ih, w_hh, b_ih, b_hh, g_2, b_2,
                                     w_f1, b_f1, w_f2, b_f2, query, out_q, 0);
}

// Round 4
// 739.414 us; speedup vs baseline: 1.4442x; 1.2753x over previous
//
#include <hip/hip_runtime.h>
#include <math.h>

#define NB 32
#define HW 4096
#define NS 16
#define EDIM 256
#define FFND 1024
#define EPS_LN 1e-5f
#define EPS_ATTN 1e-5f
#define BPB 16            // sub-blocks per batch in bigpass
#define RPB 256           // rows per bigpass block
#define TROWS 32          // rows per barrier-tile inside bigpass

__device__ __forceinline__ float sigmoidf_(float x) { return 1.0f / (1.0f + __expf(-x)); }
__device__ __forceinline__ float gelu_(float x) {
    float x3 = x * x * x;
    return 0.5f * x * (1.0f + tanhf(0.7978845608028654f * (x + 0.044715f * x3)));
}

// W[j][c] = scale * sum_e w_q[e][j] * w_k[e][c]   (scale = 256^-0.5 = 1/16)
__global__ void k_prep(const float* __restrict__ w_q, const float* __restrict__ w_k,
                       float* __restrict__ W) {
    const int j = blockIdx.x;
    const int c = threadIdx.x;
    float acc = 0.f;
    for (int e = 0; e < EDIM; ++e)
        acc += w_q[e * EDIM + j] * w_k[e * EDIM + c];
    W[j * EDIM + c] = acc * 0.0625f;
}

// Iteration-0 only: qn = LN(query_row); qpk = qn @ W; gq/bq scalars.
__global__ void k_qproj(const float* __restrict__ qsrc, const float* __restrict__ g_q,
                        const float* __restrict__ b_q, const float* __restrict__ W,
                        const float* __restrict__ g_kv, const float* __restrict__ b_kv,
                        float* __restrict__ qpk, float* __restrict__ gqbq) {
    const int row = blockIdx.x;   // 0..511  (= b*16 + s)
    const int t = threadIdx.x;
    __shared__ float qn[EDIM];
    __shared__ float red[16];
    const float v = qsrc[(size_t)row * EDIM + t];
    float s = v, ss = v * v;
#pragma unroll
    for (int m = 1; m < 64; m <<= 1) { s += __shfl_xor(s, m); ss += __shfl_xor(ss, m); }
    const int wave = t >> 6, lane = t & 63;
    if (lane == 0) { red[wave] = s; red[8 + wave] = ss; }
    __syncthreads();
    const float st = red[0] + red[1] + red[2] + red[3];
    const float sst = red[8] + red[9] + red[10] + red[11];
    const float mean = st * (1.0f / EDIM);
    const float rstd = rsqrtf(sst * (1.0f / EDIM) - mean * mean + EPS_LN);
    qn[t] = (v - mean) * rstd * g_q[t] + b_q[t];
    __syncthreads();
    float acc = 0.f;
    for (int j = 0; j < EDIM; ++j)
        acc += qn[j] * W[j * EDIM + t];
    qpk[(size_t)row * EDIM + t] = acc;
    float u = acc * g_kv[t];
    float w2 = acc * b_kv[t];
#pragma unroll
    for (int m = 1; m < 64; m <<= 1) { u += __shfl_xor(u, m); w2 += __shfl_xor(w2, m); }
    __syncthreads();
    if (lane == 0) { red[wave] = u; red[8 + wave] = w2; }
    __syncthreads();
    if (t == 0) {
        const int b = row >> 4, sl = row & 15;
        gqbq[b * 32 + sl] = red[0] + red[1] + red[2] + red[3];
        gqbq[b * 32 + 16 + sl] = red[8] + red[9] + red[10] + red[11];
    }
}

// Streaming pass v3: block-cooperative 32-row tiles.
// Phase A: 2 rows/lane (rp=lane>>4, j=lane&15), global read ONCE + stage to LDS,
//          dot vs G (LDS), 4-step shfl reduce, softmax, weights -> wrec.
// Phase B: slot-split waves (wave w owns slots 4w..4w+3), lane = channel quad,
//          rank-4 accumulate from staged x. acc[4][4] per lane.
template <bool LAST>
__global__ __launch_bounds__(256, 4) void k_bigpass(
    const float* __restrict__ input, const float* __restrict__ qpk,
    const float* __restrict__ gqbq, const float* __restrict__ g_kv,
    float* __restrict__ pacc, float* __restrict__ psum, float* __restrict__ attn_out) {
    const int b = blockIdx.x >> 4;
    const int sub = blockIdx.x & 15;
    const int t = threadIdx.x;
    const int w = t >> 6;
    const int lane = t & 63;
    const int rp = lane >> 4;   // row-pair index within wave (0..3)
    const int j = lane & 15;    // channel 16th (16 floats per lane per row)

    __shared__ __align__(16) float G[NS][EDIM];        // 16 KB: g_kv * qpk[b]
    __shared__ __align__(16) float stage[TROWS][264];  // 33 KB: padded x tile
    __shared__ __align__(16) float wrec[TROWS][20];    // attn[16], rstd, rstd*mean
    __shared__ float gqbq_s[2][NS];

    // prologue: G = g_kv (broadcast over s) * qpk[b]
#pragma unroll
    for (int i = 0; i < 4; ++i) {
        const int idx = i * 1024 + t * 4;
        const float4 qv = *reinterpret_cast<const float4*>(qpk + (size_t)b * 4096 + idx);
        const float4 gv = *reinterpret_cast<const float4*>(g_kv + (idx & 255));
        *reinterpret_cast<float4*>(&G[0][0] + idx) =
            make_float4(qv.x * gv.x, qv.y * gv.y, qv.z * gv.z, qv.w * gv.w);
    }
    if (t < 32) gqbq_s[t >> 4][t & 15] = gqbq[b * 32 + t];
    __syncthreads();

    float acc[4][4];
    float S[4], A[4];
#pragma unroll
    for (int si = 0; si < 4; ++si) {
        acc[si][0] = acc[si][1] = acc[si][2] = acc[si][3] = 0.f;
        S[si] = 0.f; A[si] = 0.f;
    }

    const int rowbase = sub * RPB;
    const int lrow = w * 8 + rp * 2;   // local row (even) this lane-pair owns in phase A
#pragma unroll 1
    for (int tt = 0; tt < RPB / TROWS; ++tt) {
        const int grow = rowbase + tt * TROWS + lrow;   // global row (row_a)
        const float* xa = input + ((size_t)b * HW + grow) * EDIM;

        // ---- phase A ----
        float pa[NS], pb[NS];
#pragma unroll
        for (int s = 0; s < NS; ++s) { pa[s] = 0.f; pb[s] = 0.f; }
        float s1a = 0.f, s2a = 0.f, s1b = 0.f, s2b = 0.f;
#pragma unroll
        for (int c = 0; c < 4; ++c) {
            const int off = (c * 16 + j) * 4;
            const float4 xA = *reinterpret_cast<const float4*>(xa + off);
            const float4 xB = *reinterpret_cast<const float4*>(xa + EDIM + off);
            *reinterpret_cast<float4*>(&stage[lrow][off]) = xA;
            *reinterpret_cast<float4*>(&stage[lrow + 1][off]) = xB;
            s1a += xA.x + xA.y + xA.z + xA.w;
            s2a += xA.x * xA.x + xA.y * xA.y + xA.z * xA.z + xA.w * xA.w;
            s1b += xB.x + xB.y + xB.z + xB.w;
            s2b += xB.x * xB.x + xB.y * xB.y + xB.z * xB.z + xB.w * xB.w;
#pragma unroll
            for (int s = 0; s < NS; ++s) {
                const float4 gg = *reinterpret_cast<const float4*>(&G[s][off]);
                pa[s] += xA.x * gg.x + xA.y * gg.y + xA.z * gg.z + xA.w * gg.w;
                pb[s] += xB.x * gg.x + xB.y * gg.y + xB.z * gg.z + xB.w * gg.w;
            }
        }
#pragma unroll
        for (int m = 1; m < 16; m <<= 1) {
            s1a += __shfl_xor(s1a, m); s2a += __shfl_xor(s2a, m);
            s1b += __shfl_xor(s1b, m); s2b += __shfl_xor(s2b, m);
#pragma unroll
            for (int s = 0; s < NS; ++s) {
                pa[s] += __shfl_xor(pa[s], m);
                pb[s] += __shfl_xor(pb[s], m);
            }
        }
        const float meanA = s1a * (1.0f / EDIM);
        const float rstdA = rsqrtf(s2a * (1.0f / EDIM) - meanA * meanA + EPS_LN);
        const float meanB = s1b * (1.0f / EDIM);
        const float rstdB = rsqrtf(s2b * (1.0f / EDIM) - meanB * meanB + EPS_LN);
        float mxa = -1e30f, mxb = -1e30f;
#pragma unroll
        for (int s = 0; s < NS; ++s) {
            pa[s] = rstdA * (pa[s] - meanA * gqbq_s[0][s]) + gqbq_s[1][s];
            pb[s] = rstdB * (pb[s] - meanB * gqbq_s[0][s]) + gqbq_s[1][s];
            mxa = fmaxf(mxa, pa[s]); mxb = fmaxf(mxb, pb[s]);
        }
        float ta = 0.f, tb = 0.f;
#pragma unroll
        for (int s = 0; s < NS; ++s) {
            pa[s] = __expf(pa[s] - mxa); ta += pa[s];
            pb[s] = __expf(pb[s] - mxb); tb += pb[s];
        }
        const float ia = 1.0f / ta, ib = 1.0f / tb;
#pragma unroll
        for (int s = 0; s < NS; ++s) { pa[s] *= ia; pb[s] *= ib; }

        if (j == 0) {
#pragma unroll
            for (int sq = 0; sq < 4; ++sq)
                *reinterpret_cast<float4*>(&wrec[lrow][sq * 4]) =
                    make_float4(pa[sq * 4], pa[sq * 4 + 1], pa[sq * 4 + 2], pa[sq * 4 + 3]);
            wrec[lrow][16] = rstdA;
            wrec[lrow][17] = rstdA * meanA;
        } else if (j == 1) {
#pragma unroll
            for (int sq = 0; sq < 4; ++sq)
                *reinterpret_cast<float4*>(&wrec[lrow + 1][sq * 4]) =
                    make_float4(pb[sq * 4], pb[sq * 4 + 1], pb[sq * 4 + 2], pb[sq * 4 + 3]);
            wrec[lrow + 1][16] = rstdB;
            wrec[lrow + 1][17] = rstdB * meanB;
        }
        if (LAST) {
            if (j == 0) {
#pragma unroll
                for (int s = 0; s < NS; ++s)
                    attn_out[((size_t)(b * NS + s)) * HW + grow] = pa[s];
            } else if (j == 1) {
#pragma unroll
                for (int s = 0; s < NS; ++s)
                    attn_out[((size_t)(b * NS + s)) * HW + grow + 1] = pb[s];
            }
        }
        __syncthreads();

        // ---- phase B: wave w accumulates slots 4w..4w+3 over all 32 rows ----
        {
            const int ch = lane * 4;
            const int sbase = w * 4;
#pragma unroll 4
            for (int r = 0; r < TROWS; ++r) {
                const float4 xv = *reinterpret_cast<const float4*>(&stage[r][ch]);
                const float4 at = *reinterpret_cast<const float4*>(&wrec[r][sbase]);
                const float rr = wrec[r][16];
                const float rm = wrec[r][17];
                float wg;
                wg = at.x * rr;
                acc[0][0] += wg * xv.x; acc[0][1] += wg * xv.y;
                acc[0][2] += wg * xv.z; acc[0][3] += wg * xv.w;
                S[0] += at.x; A[0] += at.x * rm;
                wg = at.y * rr;
                acc[1][0] += wg * xv.x; acc[1][1] += wg * xv.y;
                acc[1][2] += wg * xv.z; acc[1][3] += wg * xv.w;
                S[1] += at.y; A[1] += at.y * rm;
                wg = at.z * rr;
                acc[2][0] += wg * xv.x; acc[2][1] += wg * xv.y;
                acc[2][2] += wg * xv.z; acc[2][3] += wg * xv.w;
                S[2] += at.z; A[2] += at.z * rm;
                wg = at.w * rr;
                acc[3][0] += wg * xv.x; acc[3][1] += wg * xv.y;
                acc[3][2] += wg * xv.z; acc[3][3] += wg * xv.w;
                S[3] += at.w; A[3] += at.w * rm;
            }
        }
        __syncthreads();
    }

    // epilogue: each wave writes its own 4 slots (no cross-wave combine needed)
#pragma unroll
    for (int si = 0; si < 4; ++si) {
        *reinterpret_cast<float4*>(
            pacc + ((size_t)blockIdx.x * NS + w * 4 + si) * EDIM + lane * 4) =
            make_float4(acc[si][0], acc[si][1], acc[si][2], acc[si][3]);
    }
    if (lane == 0) {
#pragma unroll
        for (int si = 0; si < 4; ++si) {
            psum[blockIdx.x * 32 + w * 4 + si] = S[si];
            psum[blockIdx.x * 32 + 16 + w * 4 + si] = A[si];
        }
    }
}

// Fused: k_mid (partial reduce + w_v proj) + GRU + LN + FFN + next-iter qproj.
// 128 blocks x 4 rows each; block bid -> rows b*16 + sg*4 .. +3.
__global__ __launch_bounds__(256) void k_slot(
    const float* __restrict__ pacc, const float* __restrict__ psum,
    const float* __restrict__ w_v, const float* __restrict__ g_kv,
    const float* __restrict__ b_kv,
    const float* __restrict__ qsrc,
    const float* __restrict__ w_ih, const float* __restrict__ w_hh,
    const float* __restrict__ b_ih, const float* __restrict__ b_hh,
    const float* __restrict__ g_2, const float* __restrict__ b_2,
    const float* __restrict__ w_f1, const float* __restrict__ b_f1,
    const float* __restrict__ w_f2, const float* __restrict__ b_f2,
    const float* __restrict__ query,
    const float* __restrict__ g_q, const float* __restrict__ b_q,
    const float* __restrict__ W,
    float* __restrict__ q_out, float* __restrict__ qpk, float* __restrict__ gqbq,
    int adjust, int do_qproj) {
    const int bid = blockIdx.x;
    const int b = bid >> 2;
    const int sg = bid & 3;
    const int row0 = b * NS + sg * 4;
    const int t = threadIdx.x;
    const int wave = t >> 6, lane = t & 63;

    __shared__ __align__(16) float upd[4][EDIM];
    __shared__ __align__(16) float qrow[4][EDIM];
    __shared__ __align__(16) float gi[4][3 * EDIM];
    __shared__ __align__(16) float gh[4][3 * EDIM];
    __shared__ __align__(16) float slots[4][EDIM];
    __shared__ __align__(16) float ln2[4][EDIM];
    __shared__ __align__(16) float h1[4][FFND];
    __shared__ float sSA[4][2];
    __shared__ float red2[4][8];

    // ---- mid: reduce partials, normalize, fold LN(g,b) back in ----
    if (t < 8) {
        const int r = t & 3;
        const int isA = t >> 2;
        float v = 0.f;
        for (int p_ = 0; p_ < BPB; ++p_)
            v += psum[(b * BPB + p_) * 32 + isA * 16 + sg * 4 + r];
        sSA[r][isA] = v;
    }
#pragma unroll
    for (int r = 0; r < 4; ++r)
        qrow[r][t] = qsrc[(size_t)(row0 + r) * EDIM + t];
    __syncthreads();
#pragma unroll
    for (int r = 0; r < 4; ++r) {
        float V = 0.f;
        for (int p_ = 0; p_ < BPB; ++p_)
            V += pacc[((size_t)(b * BPB + p_) * NS + sg * 4 + r) * EDIM + t];
        const float Sv = sSA[r][0], Av = sSA[r][1];
        ln2[r][t] = (g_kv[t] * (V - Av) + b_kv[t] * Sv) / (Sv + EPS_ATTN);  // ub
    }
    __syncthreads();
    {   // updates = ub @ w_v.T
        float accV[4] = {0.f, 0.f, 0.f, 0.f};
        for (int jj = 0; jj < EDIM; jj += 4) {
            const float4 wv = *reinterpret_cast<const float4*>(w_v + (size_t)t * EDIM + jj);
#pragma unroll
            for (int r = 0; r < 4; ++r) {
                const float4 u = *reinterpret_cast<const float4*>(&ln2[r][jj]);
                accV[r] += u.x * wv.x + u.y * wv.y + u.z * wv.z + u.w * wv.w;
            }
        }
#pragma unroll
        for (int r = 0; r < 4; ++r) upd[r][t] = accV[r];
    }
    __syncthreads();

    {   // gi = upd @ w_ih.T + b_ih ; gh = qrow @ w_hh.T + b_hh
        float accI[3][4], accH[3][4];
#pragma unroll
        for (int k = 0; k < 3; ++k)
#pragma unroll
            for (int r = 0; r < 4; ++r) { accI[k][r] = 0.f; accH[k][r] = 0.f; }
        for (int jj = 0; jj < EDIM; jj += 4) {
            float4 u[4], qv[4];
#pragma unroll
            for (int r = 0; r < 4; ++r) {
                u[r] = *reinterpret_cast<const float4*>(&upd[r][jj]);
                qv[r] = *reinterpret_cast<const float4*>(&qrow[r][jj]);
            }
#pragma unroll
            for (int k = 0; k < 3; ++k) {
                const float4 wi = *reinterpret_cast<const float4*>(&w_ih[(size_t)(k * EDIM + t) * EDIM + jj]);
                const float4 wh = *reinterpret_cast<const float4*>(&w_hh[(size_t)(k * EDIM + t) * EDIM + jj]);
#pragma unroll
                for (int r = 0; r < 4; ++r) {
                    accI[k][r] += u[r].x * wi.x + u[r].y * wi.y + u[r].z * wi.z + u[r].w * wi.w;
                    accH[k][r] += qv[r].x * wh.x + qv[r].y * wh.y + qv[r].z * wh.z + qv[r].w * wh.w;
                }
            }
        }
#pragma unroll
        for (int k = 0; k < 3; ++k) {
            const float bi = b_ih[k * EDIM + t];
            const float bh = b_hh[k * EDIM + t];
#pragma unroll
            for (int r = 0; r < 4; ++r) {
                gi[r][k * EDIM + t] = accI[k][r] + bi;
                gh[r][k * EDIM + t] = accH[k][r] + bh;
            }
        }
    }
    __syncthreads();

#pragma unroll
    for (int r = 0; r < 4; ++r) {   // GRU gates
        const float ir = gi[r][t], iz = gi[r][EDIM + t], inn = gi[r][2 * EDIM + t];
        const float hr = gh[r][t], hz = gh[r][EDIM + t], hn = gh[r][2 * EDIM + t];
        const float h = qrow[r][t];
        const float rg = sigmoidf_(ir + hr);
        const float z = sigmoidf_(iz + hz);
        const float n = tanhf(inn + rg * hn);
        slots[r][t] = (1.0f - z) * n + z * h;
    }
    __syncthreads();

    {   // LN(slots) per row: one wave per row
        const float4 v = *reinterpret_cast<const float4*>(&slots[wave][lane * 4]);
        float s1 = v.x + v.y + v.z + v.w;
        float s2 = v.x * v.x + v.y * v.y + v.z * v.z + v.w * v.w;
#pragma unroll
        for (int m = 1; m < 64; m <<= 1) { s1 += __shfl_xor(s1, m); s2 += __shfl_xor(s2, m); }
        const float mean = s1 * (1.0f / EDIM);
        const float rstd = rsqrtf(s2 * (1.0f / EDIM) - mean * mean + EPS_LN);
        const float4 gg = *reinterpret_cast<const float4*>(g_2 + lane * 4);
        const float4 bb = *reinterpret_cast<const float4*>(b_2 + lane * 4);
        float4 o;
        o.x = (v.x - mean) * rstd * gg.x + bb.x;
        o.y = (v.y - mean) * rstd * gg.y + bb.y;
        o.z = (v.z - mean) * rstd * gg.z + bb.z;
        o.w = (v.w - mean) * rstd * gg.w + bb.w;
        *reinterpret_cast<float4*>(&ln2[wave][lane * 4]) = o;
    }
    __syncthreads();

    {   // h1 = gelu(ln2 @ w_f1.T + b_f1)
        float acc[4][4];
#pragma unroll
        for (int k = 0; k < 4; ++k)
#pragma unroll
            for (int r = 0; r < 4; ++r) acc[k][r] = 0.f;
        for (int jj = 0; jj < EDIM; jj += 4) {
            float4 l[4];
#pragma unroll
            for (int r = 0; r < 4; ++r) l[r] = *reinterpret_cast<const float4*>(&ln2[r][jj]);
#pragma unroll
            for (int k = 0; k < 4; ++k) {
                const float4 wv = *reinterpret_cast<const float4*>(&w_f1[(size_t)(k * EDIM + t) * EDIM + jj]);
#pragma unroll
                for (int r = 0; r < 4; ++r)
                    acc[k][r] += l[r].x * wv.x + l[r].y * wv.y + l[r].z * wv.z + l[r].w * wv.w;
            }
        }
#pragma unroll
        for (int k = 0; k < 4; ++k) {
            const float bf = b_f1[k * EDIM + t];
#pragma unroll
            for (int r = 0; r < 4; ++r) h1[r][k * EDIM + t] = gelu_(acc[k][r] + bf);
        }
    }
    __syncthreads();

    float qn_r[4];
    {   // q = slots + h1 @ w_f2.T + b_f2  (+ optional stop-grad forward identity)
        float acc[4] = {0.f, 0.f, 0.f, 0.f};
        for (int jj = 0; jj < FFND; jj += 4) {
            const float4 wv = *reinterpret_cast<const float4*>(&w_f2[(size_t)t * FFND + jj]);
#pragma unroll
            for (int r = 0; r < 4; ++r) {
                const float4 hh = *reinterpret_cast<const float4*>(&h1[r][jj]);
                acc[r] += hh.x * wv.x + hh.y * wv.y + hh.z * wv.z + hh.w * wv.w;
            }
        }
        const float bf = b_f2[t];
#pragma unroll
        for (int r = 0; r < 4; ++r) {
            float qn = slots[r][t] + acc[r] + bf;
            if (adjust) {
                const float qq = query[(size_t)(row0 + r) * EDIM + t];
                qn = (qn + qq) - qq;   // replicate (sg(q)+query)-sg(query) forward rounding
            }
            q_out[(size_t)(row0 + r) * EDIM + t] = qn;
            qn_r[r] = qn;
        }
    }

    if (!do_qproj) return;

    // ---- fused qproj for next iteration ----
    {   // LN over each of the 4 rows (values live per-thread in qn_r)
        float sr[4], ssr[4];
#pragma unroll
        for (int r = 0; r < 4; ++r) { sr[r] = qn_r[r]; ssr[r] = qn_r[r] * qn_r[r]; }
#pragma unroll
        for (int m = 1; m < 64; m <<= 1) {
#pragma unroll
            for (int r = 0; r < 4; ++r) {
                sr[r] += __shfl_xor(sr[r], m);
                ssr[r] += __shfl_xor(ssr[r], m);
            }
        }
        __syncthreads();   // ln2 free (h1 consumed it)
        if (lane == 0) {
#pragma unroll
            for (int r = 0; r < 4; ++r) { red2[wave][r] = sr[r]; red2[wave][4 + r] = ssr[r]; }
        }
        __syncthreads();
#pragma unroll
        for (int r = 0; r < 4; ++r) {
            const float st = red2[0][r] + red2[1][r] + red2[2][r] + red2[3][r];
            const float sst = red2[0][4 + r] + red2[1][4 + r] + red2[2][4 + r] + red2[3][4 + r];
            const float mean = st * (1.0f / EDIM);
            const float rstd = rsqrtf(sst * (1.0f / EDIM) - mean * mean + EPS_LN);
            ln2[r][t] = (qn_r[r] - mean) * rstd * g_q[t] + b_q[t];
        }
    }
    __syncthreads();

    float qv[4] = {0.f, 0.f, 0.f, 0.f};
    for (int jj = 0; jj < EDIM; ++jj) {
        const float wv = W[(size_t)jj * EDIM + t];
#pragma unroll
        for (int r = 0; r < 4; ++r) qv[r] += ln2[r][jj] * wv;
    }
#pragma unroll
    for (int r = 0; r < 4; ++r)
        qpk[(size_t)(row0 + r) * EDIM + t] = qv[r];

    {   // gq/bq scalars
        float u[4], w2[4];
#pragma unroll
        for (int r = 0; r < 4; ++r) { u[r] = qv[r] * g_kv[t]; w2[r] = qv[r] * b_kv[t]; }
#pragma unroll
        for (int m = 1; m < 64; m <<= 1) {
#pragma unroll
            for (int r = 0; r < 4; ++r) {
                u[r] += __shfl_xor(u[r], m);
                w2[r] += __shfl_xor(w2[r], m);
            }
        }
        __syncthreads();
        if (lane == 0) {
#pragma unroll
            for (int r = 0; r < 4; ++r) { red2[wave][r] = u[r]; red2[wave][4 + r] = w2[r]; }
        }
        __syncthreads();
        if (t < 4) {
            gqbq[b * 32 + sg * 4 + t] =
                red2[0][t] + red2[1][t] + red2[2][t] + red2[3][t];
            gqbq[b * 32 + 16 + sg * 4 + t] =
                red2[0][4 + t] + red2[1][4 + t] + red2[2][4 + t] + red2[3][4 + t];
        }
    }
}

extern "C" void kernel_launch(void* const* d_in, const int* in_sizes, int n_in,
                              void* d_out, int out_size, void* d_ws, size_t ws_size,
                              hipStream_t stream) {
    const float* input = (const float*)d_in[0];
    const float* query = (const float*)d_in[1];
    const float* g_kv = (const float*)d_in[2];
    const float* b_kv = (const float*)d_in[3];
    const float* w_k = (const float*)d_in[4];
    const float* w_v = (const float*)d_in[5];
    const float* g_q = (const float*)d_in[6];
    const float* b_q = (const float*)d_in[7];
    const float* w_q = (const float*)d_in[8];
    const float* w_ih = (const float*)d_in[9];
    const float* w_hh = (const float*)d_in[10];
    const float* b_ih = (const float*)d_in[11];
    const float* b_hh = (const float*)d_in[12];
    const float* g_2 = (const float*)d_in[13];
    const float* b_2 = (const float*)d_in[14];
    const float* w_f1 = (const float*)d_in[15];
    const float* b_f1 = (const float*)d_in[16];
    const float* w_f2 = (const float*)d_in[17];
    const float* b_f2 = (const float*)d_in[18];

    float* ws = (float*)d_ws;
    float* W = ws;        ws += 256 * 256;
    float* qpk = ws;      ws += 512 * 256;
    float* gqbq = ws;     ws += NB * 32;
    float* pacc = ws;     ws += (size_t)NB * BPB * NS * EDIM;   // 512*16*256
    float* psum = ws;     ws += NB * BPB * 32;
    float* q_ws = ws;     ws += 512 * 256;

    float* out_q = (float*)d_out;
    float* out_attn = out_q + (size_t)NB * NS * EDIM;

    k_prep<<<256, 256, 0, stream>>>(w_q, w_k, W);
    k_qproj<<<512, 256, 0, stream>>>(query, g_q, b_q, W, g_kv, b_kv, qpk, gqbq);

    // ---- iteration 0 ----
    k_bigpass<false><<<NB * BPB, 256, 0, stream>>>(input, qpk, gqbq, g_kv, pacc, psum, nullptr);
    k_slot<<<128, 256, 0, stream>>>(pacc, psum, w_v, g_kv, b_kv,
                                    query, w_ih, w_hh, b_ih, b_hh, g_2, b_2,
                                    w_f1, b_f1, w_f2, b_f2, query, g_q, b_q, W,
                                    q_ws, qpk, gqbq, 0, 1);

    // ---- iteration 1 (adjust: bi-level stop-grad forward identity) ----
    k_bigpass<false><<<NB * BPB, 256, 0, stream>>>(input, qpk, gqbq, g_kv, pacc, psum, nullptr);
    k_slot<<<128, 256, 0, stream>>>(pacc, psum, w_v, g_kv, b_kv,
                                    q_ws, w_ih, w_hh, b_ih, b_hh, g_2, b_2,
                                    w_f1, b_f1, w_f2, b_f2, query, g_q, b_q, W,
                                    q_ws, qpk, gqbq, 1, 1);

    // ---- iteration 2 (LAST: attn to output; q straight to d_out; no qproj) ----
    k_bigpass<true><<<NB * BPB, 256, 0, stream>>>(input, qpk, gqbq, g_kv, pacc, psum, out_attn);
    k_slot<<<128, 256, 0, stream>>>(pacc, psum, w_v, g_kv, b_kv,
                                    q_ws, w_ih, w_hh, b_ih, b_hh, g_2, b_2,
                                    w_f1, b_f1, w_f2, b_f2, query, g_q, b_q, W,
                                    out_q, qpk, gqbq, 0, 0);
}

// Round 5
// 578.284 us; speedup vs baseline: 1.8466x; 1.2786x over previous
//
#include <hip/hip_runtime.h>
#include <math.h>

#define NB 32
#define HW 4096
#define NS 16
#define EDIM 256
#define FFND 1024
#define EPS_LN 1e-5f
#define EPS_ATTN 1e-5f
#define BPB 16            // sub-blocks per batch in bigpass
#define RPB 256           // rows per bigpass block
#define TROWS 32          // rows per barrier-tile inside bigpass

__device__ __forceinline__ float sigmoidf_(float x) { return 1.0f / (1.0f + __expf(-x)); }
__device__ __forceinline__ float gelu_(float x) {
    float x3 = x * x * x;
    return 0.5f * x * (1.0f + tanhf(0.7978845608028654f * (x + 0.044715f * x3)));
}

// W[j][c] = scale * sum_e w_q[e][j] * w_k[e][c]   (scale = 256^-0.5 = 1/16)
__global__ void k_prep(const float* __restrict__ w_q, const float* __restrict__ w_k,
                       float* __restrict__ W) {
    const int j = blockIdx.x;
    const int c = threadIdx.x;
    float acc = 0.f;
    for (int e = 0; e < EDIM; ++e)
        acc += w_q[e * EDIM + j] * w_k[e * EDIM + c];
    W[j * EDIM + c] = acc * 0.0625f;
}

// Tiled transpose: src[R][C] -> dst[C][R].  R,C multiples of 64. 64x64 tiles.
__global__ __launch_bounds__(256) void k_tr(const float* __restrict__ src,
                                            float* __restrict__ dst, int R, int C) {
    __shared__ float tile[64][65];
    const int tilesC = C >> 6;
    const int tR = (blockIdx.x / tilesC) << 6;
    const int tC = (blockIdx.x % tilesC) << 6;
    const int t = threadIdx.x;
    {
        const int r = t >> 2;
        const int c0 = (t & 3) << 4;
#pragma unroll
        for (int i = 0; i < 16; i += 4) {
            const float4 v = *reinterpret_cast<const float4*>(src + (size_t)(tR + r) * C + tC + c0 + i);
            tile[r][c0 + i] = v.x; tile[r][c0 + i + 1] = v.y;
            tile[r][c0 + i + 2] = v.z; tile[r][c0 + i + 3] = v.w;
        }
    }
    __syncthreads();
    {
        const int c = t >> 2;
        const int r0 = (t & 3) << 4;
#pragma unroll
        for (int i = 0; i < 16; ++i)
            dst[(size_t)(tC + c) * R + tR + r0 + i] = tile[r0 + i][c];
    }
}

// Iteration-0 only: qn = LN(query_row); qpk = qn @ W; gq/bq scalars.
__global__ void k_qproj(const float* __restrict__ qsrc, const float* __restrict__ g_q,
                        const float* __restrict__ b_q, const float* __restrict__ W,
                        const float* __restrict__ g_kv, const float* __restrict__ b_kv,
                        float* __restrict__ qpk, float* __restrict__ gqbq) {
    const int row = blockIdx.x;   // 0..511  (= b*16 + s)
    const int t = threadIdx.x;
    __shared__ float qn[EDIM];
    __shared__ float red[16];
    const float v = qsrc[(size_t)row * EDIM + t];
    float s = v, ss = v * v;
#pragma unroll
    for (int m = 1; m < 64; m <<= 1) { s += __shfl_xor(s, m); ss += __shfl_xor(ss, m); }
    const int wave = t >> 6, lane = t & 63;
    if (lane == 0) { red[wave] = s; red[8 + wave] = ss; }
    __syncthreads();
    const float st = red[0] + red[1] + red[2] + red[3];
    const float sst = red[8] + red[9] + red[10] + red[11];
    const float mean = st * (1.0f / EDIM);
    const float rstd = rsqrtf(sst * (1.0f / EDIM) - mean * mean + EPS_LN);
    qn[t] = (v - mean) * rstd * g_q[t] + b_q[t];
    __syncthreads();
    float acc = 0.f;
    for (int j = 0; j < EDIM; ++j)
        acc += qn[j] * W[j * EDIM + t];
    qpk[(size_t)row * EDIM + t] = acc;
    float u = acc * g_kv[t];
    float w2 = acc * b_kv[t];
#pragma unroll
    for (int m = 1; m < 64; m <<= 1) { u += __shfl_xor(u, m); w2 += __shfl_xor(w2, m); }
    __syncthreads();
    if (lane == 0) { red[wave] = u; red[8 + wave] = w2; }
    __syncthreads();
    if (t == 0) {
        const int b = row >> 4, sl = row & 15;
        gqbq[b * 32 + sl] = red[0] + red[1] + red[2] + red[3];
        gqbq[b * 32 + 16 + sl] = red[8] + red[9] + red[10] + red[11];
    }
}

// Streaming pass v3 (unchanged from r4): block-cooperative 32-row tiles.
template <bool LAST>
__global__ __launch_bounds__(256, 4) void k_bigpass(
    const float* __restrict__ input, const float* __restrict__ qpk,
    const float* __restrict__ gqbq, const float* __restrict__ g_kv,
    float* __restrict__ pacc, float* __restrict__ psum, float* __restrict__ attn_out) {
    const int b = blockIdx.x >> 4;
    const int sub = blockIdx.x & 15;
    const int t = threadIdx.x;
    const int w = t >> 6;
    const int lane = t & 63;
    const int rp = lane >> 4;
    const int j = lane & 15;

    __shared__ __align__(16) float G[NS][EDIM];
    __shared__ __align__(16) float stage[TROWS][264];
    __shared__ __align__(16) float wrec[TROWS][20];
    __shared__ float gqbq_s[2][NS];

#pragma unroll
    for (int i = 0; i < 4; ++i) {
        const int idx = i * 1024 + t * 4;
        const float4 qv = *reinterpret_cast<const float4*>(qpk + (size_t)b * 4096 + idx);
        const float4 gv = *reinterpret_cast<const float4*>(g_kv + (idx & 255));
        *reinterpret_cast<float4*>(&G[0][0] + idx) =
            make_float4(qv.x * gv.x, qv.y * gv.y, qv.z * gv.z, qv.w * gv.w);
    }
    if (t < 32) gqbq_s[t >> 4][t & 15] = gqbq[b * 32 + t];
    __syncthreads();

    float acc[4][4];
    float S[4], A[4];
#pragma unroll
    for (int si = 0; si < 4; ++si) {
        acc[si][0] = acc[si][1] = acc[si][2] = acc[si][3] = 0.f;
        S[si] = 0.f; A[si] = 0.f;
    }

    const int rowbase = sub * RPB;
    const int lrow = w * 8 + rp * 2;
#pragma unroll 1
    for (int tt = 0; tt < RPB / TROWS; ++tt) {
        const int grow = rowbase + tt * TROWS + lrow;
        const float* xa = input + ((size_t)b * HW + grow) * EDIM;

        float pa[NS], pb[NS];
#pragma unroll
        for (int s = 0; s < NS; ++s) { pa[s] = 0.f; pb[s] = 0.f; }
        float s1a = 0.f, s2a = 0.f, s1b = 0.f, s2b = 0.f;
#pragma unroll
        for (int c = 0; c < 4; ++c) {
            const int off = (c * 16 + j) * 4;
            const float4 xA = *reinterpret_cast<const float4*>(xa + off);
            const float4 xB = *reinterpret_cast<const float4*>(xa + EDIM + off);
            *reinterpret_cast<float4*>(&stage[lrow][off]) = xA;
            *reinterpret_cast<float4*>(&stage[lrow + 1][off]) = xB;
            s1a += xA.x + xA.y + xA.z + xA.w;
            s2a += xA.x * xA.x + xA.y * xA.y + xA.z * xA.z + xA.w * xA.w;
            s1b += xB.x + xB.y + xB.z + xB.w;
            s2b += xB.x * xB.x + xB.y * xB.y + xB.z * xB.z + xB.w * xB.w;
#pragma unroll
            for (int s = 0; s < NS; ++s) {
                const float4 gg = *reinterpret_cast<const float4*>(&G[s][off]);
                pa[s] += xA.x * gg.x + xA.y * gg.y + xA.z * gg.z + xA.w * gg.w;
                pb[s] += xB.x * gg.x + xB.y * gg.y + xB.z * gg.z + xB.w * gg.w;
            }
        }
#pragma unroll
        for (int m = 1; m < 16; m <<= 1) {
            s1a += __shfl_xor(s1a, m); s2a += __shfl_xor(s2a, m);
            s1b += __shfl_xor(s1b, m); s2b += __shfl_xor(s2b, m);
#pragma unroll
            for (int s = 0; s < NS; ++s) {
                pa[s] += __shfl_xor(pa[s], m);
                pb[s] += __shfl_xor(pb[s], m);
            }
        }
        const float meanA = s1a * (1.0f / EDIM);
        const float rstdA = rsqrtf(s2a * (1.0f / EDIM) - meanA * meanA + EPS_LN);
        const float meanB = s1b * (1.0f / EDIM);
        const float rstdB = rsqrtf(s2b * (1.0f / EDIM) - meanB * meanB + EPS_LN);
        float mxa = -1e30f, mxb = -1e30f;
#pragma unroll
        for (int s = 0; s < NS; ++s) {
            pa[s] = rstdA * (pa[s] - meanA * gqbq_s[0][s]) + gqbq_s[1][s];
            pb[s] = rstdB * (pb[s] - meanB * gqbq_s[0][s]) + gqbq_s[1][s];
            mxa = fmaxf(mxa, pa[s]); mxb = fmaxf(mxb, pb[s]);
        }
        float ta = 0.f, tb = 0.f;
#pragma unroll
        for (int s = 0; s < NS; ++s) {
            pa[s] = __expf(pa[s] - mxa); ta += pa[s];
            pb[s] = __expf(pb[s] - mxb); tb += pb[s];
        }
        const float ia = 1.0f / ta, ib = 1.0f / tb;
#pragma unroll
        for (int s = 0; s < NS; ++s) { pa[s] *= ia; pb[s] *= ib; }

        if (j == 0) {
#pragma unroll
            for (int sq = 0; sq < 4; ++sq)
                *reinterpret_cast<float4*>(&wrec[lrow][sq * 4]) =
                    make_float4(pa[sq * 4], pa[sq * 4 + 1], pa[sq * 4 + 2], pa[sq * 4 + 3]);
            wrec[lrow][16] = rstdA;
            wrec[lrow][17] = rstdA * meanA;
        } else if (j == 1) {
#pragma unroll
            for (int sq = 0; sq < 4; ++sq)
                *reinterpret_cast<float4*>(&wrec[lrow + 1][sq * 4]) =
                    make_float4(pb[sq * 4], pb[sq * 4 + 1], pb[sq * 4 + 2], pb[sq * 4 + 3]);
            wrec[lrow + 1][16] = rstdB;
            wrec[lrow + 1][17] = rstdB * meanB;
        }
        if (LAST) {
            if (j == 0) {
#pragma unroll
                for (int s = 0; s < NS; ++s)
                    attn_out[((size_t)(b * NS + s)) * HW + grow] = pa[s];
            } else if (j == 1) {
#pragma unroll
                for (int s = 0; s < NS; ++s)
                    attn_out[((size_t)(b * NS + s)) * HW + grow + 1] = pb[s];
            }
        }
        __syncthreads();

        {
            const int ch = lane * 4;
            const int sbase = w * 4;
#pragma unroll 4
            for (int r = 0; r < TROWS; ++r) {
                const float4 xv = *reinterpret_cast<const float4*>(&stage[r][ch]);
                const float4 at = *reinterpret_cast<const float4*>(&wrec[r][sbase]);
                const float rr = wrec[r][16];
                const float rm = wrec[r][17];
                float wg;
                wg = at.x * rr;
                acc[0][0] += wg * xv.x; acc[0][1] += wg * xv.y;
                acc[0][2] += wg * xv.z; acc[0][3] += wg * xv.w;
                S[0] += at.x; A[0] += at.x * rm;
                wg = at.y * rr;
                acc[1][0] += wg * xv.x; acc[1][1] += wg * xv.y;
                acc[1][2] += wg * xv.z; acc[1][3] += wg * xv.w;
                S[1] += at.y; A[1] += at.y * rm;
                wg = at.z * rr;
                acc[2][0] += wg * xv.x; acc[2][1] += wg * xv.y;
                acc[2][2] += wg * xv.z; acc[2][3] += wg * xv.w;
                S[2] += at.z; A[2] += at.z * rm;
                wg = at.w * rr;
                acc[3][0] += wg * xv.x; acc[3][1] += wg * xv.y;
                acc[3][2] += wg * xv.z; acc[3][3] += wg * xv.w;
                S[3] += at.w; A[3] += at.w * rm;
            }
        }
        __syncthreads();
    }

#pragma unroll
    for (int si = 0; si < 4; ++si) {
        *reinterpret_cast<float4*>(
            pacc + ((size_t)blockIdx.x * NS + w * 4 + si) * EDIM + lane * 4) =
            make_float4(acc[si][0], acc[si][1], acc[si][2], acc[si][3]);
    }
    if (lane == 0) {
#pragma unroll
        for (int si = 0; si < 4; ++si) {
            psum[blockIdx.x * 32 + w * 4 + si] = S[si];
            psum[blockIdx.x * 32 + 16 + w * 4 + si] = A[si];
        }
    }
}

// G1: partial reduce + ub + updates = ub @ w_v.T.  grid 256: (rt 0..127) x (ct 0..1)
__global__ __launch_bounds__(256) void k_upd(
    const float* __restrict__ pacc, const float* __restrict__ psum,
    const float* __restrict__ g_kv, const float* __restrict__ b_kv,
    const float* __restrict__ w_vT, float* __restrict__ updates) {
    const int rt = blockIdx.x >> 1;
    const int ct = blockIdx.x & 1;
    const int row0 = rt * 4;
    const int b = row0 >> 4;
    const int s0 = row0 & 15;
    const int t = threadIdx.x;
    __shared__ __align__(16) float ub[4][EDIM];
    __shared__ float sSA[4][2];

    if (t < 8) {
        const int r = t & 3;
        const int isA = t >> 2;
        float v = 0.f;
        for (int p = 0; p < BPB; ++p)
            v += psum[(b * BPB + p) * 32 + isA * 16 + s0 + r];
        sSA[r][isA] = v;
    }
    __syncthreads();
#pragma unroll
    for (int r = 0; r < 4; ++r) {
        float V = 0.f;
        for (int p = 0; p < BPB; ++p)
            V += pacc[((size_t)(b * BPB + p) * NS + s0 + r) * EDIM + t];
        const float Sv = sSA[r][0], Av = sSA[r][1];
        ub[r][t] = (g_kv[t] * (V - Av) + b_kv[t] * Sv) / (Sv + EPS_ATTN);
    }
    __syncthreads();

    const int c = ct * 128 + (t & 127);
    const int half = t >> 7;       // 2 rows per thread
    const float* u0 = ub[2 * half];
    const float* u1 = ub[2 * half + 1];
    float a0 = 0.f, a1 = 0.f;
#pragma unroll 4
    for (int j = 0; j < EDIM; j += 4) {
        const float4 x0 = *reinterpret_cast<const float4*>(u0 + j);
        const float4 x1 = *reinterpret_cast<const float4*>(u1 + j);
        const float w0 = w_vT[(size_t)j * EDIM + c];
        const float w1 = w_vT[(size_t)(j + 1) * EDIM + c];
        const float w2 = w_vT[(size_t)(j + 2) * EDIM + c];
        const float w3 = w_vT[(size_t)(j + 3) * EDIM + c];
        a0 += x0.x * w0 + x0.y * w1 + x0.z * w2 + x0.w * w3;
        a1 += x1.x * w0 + x1.y * w1 + x1.z * w2 + x1.w * w3;
    }
    updates[(size_t)(row0 + 2 * half) * EDIM + c] = a0;
    updates[(size_t)(row0 + 2 * half + 1) * EDIM + c] = a1;
}

// G2a: gi = upd @ w_ih.T + b_ih (ct 0..2), gh = qprev @ w_hh.T + b_hh (ct 3..5).
// grid 768: rt = bid/6 (4 rows), ct = bid%6 (256 cols).
__global__ __launch_bounds__(256) void k_gates(
    const float* __restrict__ updates, const float* __restrict__ qprev,
    const float* __restrict__ w_ihT, const float* __restrict__ w_hhT,
    const float* __restrict__ b_ih, const float* __restrict__ b_hh,
    float* __restrict__ gig) {
    const int rt = blockIdx.x / 6;
    const int ct = blockIdx.x % 6;
    const int row0 = rt * 4;
    const int t = threadIdx.x;
    const bool ih = ct < 3;
    const int lc = (ih ? ct : ct - 3) * 256 + t;   // 0..767
    const float* __restrict__ src = ih ? updates : qprev;
    const float* __restrict__ wT = ih ? w_ihT : w_hhT;

    __shared__ __align__(16) float in4[4][EDIM];
#pragma unroll
    for (int r = 0; r < 4; ++r)
        in4[r][t] = src[(size_t)(row0 + r) * EDIM + t];
    __syncthreads();

    float a0 = 0.f, a1 = 0.f, a2 = 0.f, a3 = 0.f;
#pragma unroll 4
    for (int j = 0; j < EDIM; j += 4) {
        const float4 x0 = *reinterpret_cast<const float4*>(&in4[0][j]);
        const float4 x1 = *reinterpret_cast<const float4*>(&in4[1][j]);
        const float4 x2 = *reinterpret_cast<const float4*>(&in4[2][j]);
        const float4 x3 = *reinterpret_cast<const float4*>(&in4[3][j]);
        const float w0 = wT[(size_t)j * 768 + lc];
        const float w1 = wT[(size_t)(j + 1) * 768 + lc];
        const float w2 = wT[(size_t)(j + 2) * 768 + lc];
        const float w3 = wT[(size_t)(j + 3) * 768 + lc];
        a0 += x0.x * w0 + x0.y * w1 + x0.z * w2 + x0.w * w3;
        a1 += x1.x * w0 + x1.y * w1 + x1.z * w2 + x1.w * w3;
        a2 += x2.x * w0 + x2.y * w1 + x2.z * w2 + x2.w * w3;
        a3 += x3.x * w0 + x3.y * w1 + x3.z * w2 + x3.w * w3;
    }
    const float bias = ih ? b_ih[lc] : b_hh[lc];
    const int gcol = ih ? lc : 768 + lc;
    gig[(size_t)(row0 + 0) * 1536 + gcol] = a0 + bias;
    gig[(size_t)(row0 + 1) * 1536 + gcol] = a1 + bias;
    gig[(size_t)(row0 + 2) * 1536 + gcol] = a2 + bias;
    gig[(size_t)(row0 + 3) * 1536 + gcol] = a3 + bias;
}

// G2b: GRU pointwise + LN(slots).  grid 256 blocks x 2 rows.
__global__ __launch_bounds__(256) void k_gru(
    const float* __restrict__ gig, const float* __restrict__ qprev,
    const float* __restrict__ g_2, const float* __restrict__ b_2,
    float* __restrict__ slots, float* __restrict__ ln2s) {
    const int row0 = blockIdx.x * 2;
    const int t = threadIdx.x;
    const int wave = t >> 6, lane = t & 63;
    __shared__ float red[4][4];

    float sl[2];
#pragma unroll
    for (int r = 0; r < 2; ++r) {
        const size_t base = (size_t)(row0 + r) * 1536;
        const float ir = gig[base + t];
        const float iz = gig[base + 256 + t];
        const float inn = gig[base + 512 + t];
        const float hr = gig[base + 768 + t];
        const float hz = gig[base + 1024 + t];
        const float hn = gig[base + 1280 + t];
        const float h = qprev[(size_t)(row0 + r) * EDIM + t];
        const float rg = sigmoidf_(ir + hr);
        const float z = sigmoidf_(iz + hz);
        const float n = tanhf(inn + rg * hn);
        sl[r] = (1.0f - z) * n + z * h;
        slots[(size_t)(row0 + r) * EDIM + t] = sl[r];
    }
    float a0 = sl[0], q0 = sl[0] * sl[0], a1 = sl[1], q1 = sl[1] * sl[1];
#pragma unroll
    for (int m = 1; m < 64; m <<= 1) {
        a0 += __shfl_xor(a0, m); q0 += __shfl_xor(q0, m);
        a1 += __shfl_xor(a1, m); q1 += __shfl_xor(q1, m);
    }
    if (lane == 0) { red[wave][0] = a0; red[wave][1] = q0; red[wave][2] = a1; red[wave][3] = q1; }
    __syncthreads();
    const float S0 = red[0][0] + red[1][0] + red[2][0] + red[3][0];
    const float Q0 = red[0][1] + red[1][1] + red[2][1] + red[3][1];
    const float S1 = red[0][2] + red[1][2] + red[2][2] + red[3][2];
    const float Q1 = red[0][3] + red[1][3] + red[2][3] + red[3][3];
    const float m0 = S0 * (1.0f / EDIM);
    const float r0 = rsqrtf(Q0 * (1.0f / EDIM) - m0 * m0 + EPS_LN);
    const float m1 = S1 * (1.0f / EDIM);
    const float r1 = rsqrtf(Q1 * (1.0f / EDIM) - m1 * m1 + EPS_LN);
    const float g = g_2[t], bb = b_2[t];
    ln2s[(size_t)row0 * EDIM + t] = (sl[0] - m0) * r0 * g + bb;
    ln2s[(size_t)(row0 + 1) * EDIM + t] = (sl[1] - m1) * r1 * g + bb;
}

// G3: h1 = gelu(ln2 @ w_f1.T + b_f1). grid 512: rt = bid>>2 (4 rows), ct = bid&3 (256 cols).
__global__ __launch_bounds__(256) void k_ffn1(
    const float* __restrict__ ln2s, const float* __restrict__ w_f1T,
    const float* __restrict__ b_f1, float* __restrict__ h1) {
    const int rt = blockIdx.x >> 2;
    const int ct = blockIdx.x & 3;
    const int row0 = rt * 4;
    const int t = threadIdx.x;
    const int c = ct * 256 + t;
    __shared__ __align__(16) float in4[4][EDIM];
#pragma unroll
    for (int r = 0; r < 4; ++r)
        in4[r][t] = ln2s[(size_t)(row0 + r) * EDIM + t];
    __syncthreads();
    float a0 = 0.f, a1 = 0.f, a2 = 0.f, a3 = 0.f;
#pragma unroll 4
    for (int j = 0; j < EDIM; j += 4) {
        const float4 x0 = *reinterpret_cast<const float4*>(&in4[0][j]);
        const float4 x1 = *reinterpret_cast<const float4*>(&in4[1][j]);
        const float4 x2 = *reinterpret_cast<const float4*>(&in4[2][j]);
        const float4 x3 = *reinterpret_cast<const float4*>(&in4[3][j]);
        const float w0 = w_f1T[(size_t)j * FFND + c];
        const float w1 = w_f1T[(size_t)(j + 1) * FFND + c];
        const float w2 = w_f1T[(size_t)(j + 2) * FFND + c];
        const float w3 = w_f1T[(size_t)(j + 3) * FFND + c];
        a0 += x0.x * w0 + x0.y * w1 + x0.z * w2 + x0.w * w3;
        a1 += x1.x * w0 + x1.y * w1 + x1.z * w2 + x1.w * w3;
        a2 += x2.x * w0 + x2.y * w1 + x2.z * w2 + x2.w * w3;
        a3 += x3.x * w0 + x3.y * w1 + x3.z * w2 + x3.w * w3;
    }
    const float bf = b_f1[c];
    h1[(size_t)(row0 + 0) * FFND + c] = gelu_(a0 + bf);
    h1[(size_t)(row0 + 1) * FFND + c] = gelu_(a1 + bf);
    h1[(size_t)(row0 + 2) * FFND + c] = gelu_(a2 + bf);
    h1[(size_t)(row0 + 3) * FFND + c] = gelu_(a3 + bf);
}

// G4: q = slots + h1 @ w_f2.T + b_f2 (+adjust). grid 256 blocks x 2 rows.
__global__ __launch_bounds__(256) void k_ffn2(
    const float* __restrict__ h1, const float* __restrict__ slots,
    const float* __restrict__ w_f2T, const float* __restrict__ b_f2,
    const float* __restrict__ query, float* __restrict__ q_out, int adjust) {
    const int row0 = blockIdx.x * 2;
    const int t = threadIdx.x;
    __shared__ __align__(16) float in2[2][FFND];
#pragma unroll
    for (int r = 0; r < 2; ++r)
        *reinterpret_cast<float4*>(&in2[r][t * 4]) =
            *reinterpret_cast<const float4*>(h1 + (size_t)(row0 + r) * FFND + t * 4);
    __syncthreads();
    float a0 = 0.f, a1 = 0.f;
#pragma unroll 4
    for (int j = 0; j < FFND; j += 4) {
        const float4 x0 = *reinterpret_cast<const float4*>(&in2[0][j]);
        const float4 x1 = *reinterpret_cast<const float4*>(&in2[1][j]);
        const float w0 = w_f2T[(size_t)j * EDIM + t];
        const float w1 = w_f2T[(size_t)(j + 1) * EDIM + t];
        const float w2 = w_f2T[(size_t)(j + 2) * EDIM + t];
        const float w3 = w_f2T[(size_t)(j + 3) * EDIM + t];
        a0 += x0.x * w0 + x0.y * w1 + x0.z * w2 + x0.w * w3;
        a1 += x1.x * w0 + x1.y * w1 + x1.z * w2 + x1.w * w3;
    }
    const float bf = b_f2[t];
#pragma unroll
    for (int r = 0; r < 2; ++r) {
        float qn = slots[(size_t)(row0 + r) * EDIM + t] + (r ? a1 : a0) + bf;
        if (adjust) {
            const float qq = query[(size_t)(row0 + r) * EDIM + t];
            qn = (qn + qq) - qq;
        }
        q_out[(size_t)(row0 + r) * EDIM + t] = qn;
    }
}

// G5: qn = LN(q); qpk = qn @ W; gq/bq scalars. grid 256 blocks x 2 rows.
__global__ __launch_bounds__(256) void k_qpk(
    const float* __restrict__ qcur, const float* __restrict__ g_q,
    const float* __restrict__ b_q, const float* __restrict__ W,
    const float* __restrict__ g_kv, const float* __restrict__ b_kv,
    float* __restrict__ qpk, float* __restrict__ gqbq) {
    const int row0 = blockIdx.x * 2;
    const int t = threadIdx.x;
    const int wave = t >> 6, lane = t & 63;
    __shared__ float red[4][4];
    __shared__ __align__(16) float qn[2][EDIM];

    float v0 = qcur[(size_t)row0 * EDIM + t];
    float v1 = qcur[(size_t)(row0 + 1) * EDIM + t];
    {
        float a0 = v0, q0 = v0 * v0, a1 = v1, q1 = v1 * v1;
#pragma unroll
        for (int m = 1; m < 64; m <<= 1) {
            a0 += __shfl_xor(a0, m); q0 += __shfl_xor(q0, m);
            a1 += __shfl_xor(a1, m); q1 += __shfl_xor(q1, m);
        }
        if (lane == 0) { red[wave][0] = a0; red[wave][1] = q0; red[wave][2] = a1; red[wave][3] = q1; }
    }
    __syncthreads();
    {
        const float S0 = red[0][0] + red[1][0] + red[2][0] + red[3][0];
        const float Q0 = red[0][1] + red[1][1] + red[2][1] + red[3][1];
        const float S1 = red[0][2] + red[1][2] + red[2][2] + red[3][2];
        const float Q1 = red[0][3] + red[1][3] + red[2][3] + red[3][3];
        const float m0 = S0 * (1.0f / EDIM);
        const float r0 = rsqrtf(Q0 * (1.0f / EDIM) - m0 * m0 + EPS_LN);
        const float m1 = S1 * (1.0f / EDIM);
        const float r1 = rsqrtf(Q1 * (1.0f / EDIM) - m1 * m1 + EPS_LN);
        const float g = g_q[t], bb = b_q[t];
        qn[0][t] = (v0 - m0) * r0 * g + bb;
        qn[1][t] = (v1 - m1) * r1 * g + bb;
    }
    __syncthreads();
    float a0 = 0.f, a1 = 0.f;
#pragma unroll 4
    for (int j = 0; j < EDIM; j += 4) {
        const float4 x0 = *reinterpret_cast<const float4*>(&qn[0][j]);
        const float4 x1 = *reinterpret_cast<const float4*>(&qn[1][j]);
        const float w0 = W[(size_t)j * EDIM + t];
        const float w1 = W[(size_t)(j + 1) * EDIM + t];
        const float w2 = W[(size_t)(j + 2) * EDIM + t];
        const float w3 = W[(size_t)(j + 3) * EDIM + t];
        a0 += x0.x * w0 + x0.y * w1 + x0.z * w2 + x0.w * w3;
        a1 += x1.x * w0 + x1.y * w1 + x1.z * w2 + x1.w * w3;
    }
    qpk[(size_t)row0 * EDIM + t] = a0;
    qpk[(size_t)(row0 + 1) * EDIM + t] = a1;
    {
        const float gk = g_kv[t], bk = b_kv[t];
        float u0 = a0 * gk, w0 = a0 * bk, u1 = a1 * gk, w1 = a1 * bk;
#pragma unroll
        for (int m = 1; m < 64; m <<= 1) {
            u0 += __shfl_xor(u0, m); w0 += __shfl_xor(w0, m);
            u1 += __shfl_xor(u1, m); w1 += __shfl_xor(w1, m);
        }
        __syncthreads();
        if (lane == 0) { red[wave][0] = u0; red[wave][1] = w0; red[wave][2] = u1; red[wave][3] = w1; }
        __syncthreads();
        if (t == 0) {
            const int b = row0 >> 4;
            const int sl = row0 & 15;
            gqbq[b * 32 + sl] = red[0][0] + red[1][0] + red[2][0] + red[3][0];
            gqbq[b * 32 + 16 + sl] = red[0][1] + red[1][1] + red[2][1] + red[3][1];
            gqbq[b * 32 + sl + 1] = red[0][2] + red[1][2] + red[2][2] + red[3][2];
            gqbq[b * 32 + 16 + sl + 1] = red[0][3] + red[1][3] + red[2][3] + red[3][3];
        }
    }
}

extern "C" void kernel_launch(void* const* d_in, const int* in_sizes, int n_in,
                              void* d_out, int out_size, void* d_ws, size_t ws_size,
                              hipStream_t stream) {
    const float* input = (const float*)d_in[0];
    const float* query = (const float*)d_in[1];
    const float* g_kv = (const float*)d_in[2];
    const float* b_kv = (const float*)d_in[3];
    const float* w_k = (const float*)d_in[4];
    const float* w_v = (const float*)d_in[5];
    const float* g_q = (const float*)d_in[6];
    const float* b_q = (const float*)d_in[7];
    const float* w_q = (const float*)d_in[8];
    const float* w_ih = (const float*)d_in[9];
    const float* w_hh = (const float*)d_in[10];
    const float* b_ih = (const float*)d_in[11];
    const float* b_hh = (const float*)d_in[12];
    const float* g_2 = (const float*)d_in[13];
    const float* b_2 = (const float*)d_in[14];
    const float* w_f1 = (const float*)d_in[15];
    const float* b_f1 = (const float*)d_in[16];
    const float* w_f2 = (const float*)d_in[17];
    const float* b_f2 = (const float*)d_in[18];

    float* ws = (float*)d_ws;
    float* W = ws;        ws += 65536;
    float* qpk = ws;      ws += 131072;
    float* gqbq = ws;     ws += 1024;
    float* psum = ws;     ws += 16384;
    float* q_ws = ws;     ws += 131072;
    float* updates = ws;  ws += 131072;
    float* slots = ws;    ws += 131072;
    float* ln2s = ws;     ws += 131072;
    float* w_vT = ws;     ws += 65536;
    float* w_ihT = ws;    ws += 196608;
    float* w_hhT = ws;    ws += 196608;
    float* w_f1T = ws;    ws += 262144;
    float* w_f2T = ws;    ws += 262144;
    float* pacc = ws;     ws += 2097152;      // 8 MB; gig/h1 overlay this after k_upd
    float* gig = pacc;                        // 512*1536
    float* h1 = pacc + 786432;                // 512*1024

    float* out_q = (float*)d_out;
    float* out_attn = out_q + (size_t)NB * NS * EDIM;

    k_prep<<<256, 256, 0, stream>>>(w_q, w_k, W);
    k_tr<<<16, 256, 0, stream>>>(w_v, w_vT, 256, 256);
    k_tr<<<48, 256, 0, stream>>>(w_ih, w_ihT, 768, 256);
    k_tr<<<48, 256, 0, stream>>>(w_hh, w_hhT, 768, 256);
    k_tr<<<64, 256, 0, stream>>>(w_f1, w_f1T, 1024, 256);
    k_tr<<<64, 256, 0, stream>>>(w_f2, w_f2T, 256, 1024);
    k_qproj<<<512, 256, 0, stream>>>(query, g_q, b_q, W, g_kv, b_kv, qpk, gqbq);

    const float* qprev[3] = {query, q_ws, q_ws};
    float* qdst[3] = {q_ws, q_ws, out_q};
    const int adj[3] = {0, 1, 0};

    for (int it = 0; it < 3; ++it) {
        const bool last = (it == 2);
        if (last)
            k_bigpass<true><<<NB * BPB, 256, 0, stream>>>(input, qpk, gqbq, g_kv, pacc, psum, out_attn);
        else
            k_bigpass<false><<<NB * BPB, 256, 0, stream>>>(input, qpk, gqbq, g_kv, pacc, psum, nullptr);
        k_upd<<<256, 256, 0, stream>>>(pacc, psum, g_kv, b_kv, w_vT, updates);
        k_gates<<<768, 256, 0, stream>>>(updates, qprev[it], w_ihT, w_hhT, b_ih, b_hh, gig);
        k_gru<<<256, 256, 0, stream>>>(gig, qprev[it], g_2, b_2, slots, ln2s);
        k_ffn1<<<512, 256, 0, stream>>>(ln2s, w_f1T, b_f1, h1);
        k_ffn2<<<256, 256, 0, stream>>>(h1, slots, w_f2T, b_f2, query, qdst[it], adj[it]);
        if (!last)
            k_qpk<<<256, 256, 0, stream>>>(qdst[it], g_q, b_q, W, g_kv, b_kv, qpk, gqbq);
    }
}